// Round 1
// baseline (1608.797 us; speedup 1.0000x reference)
//
#include <hip/hip_runtime.h>
#include <hip/hip_bf16.h>
#include <stdint.h>

// Problem constants
#define BB  2
#define CC  256
#define NN  8192
#define CIc 256

typedef __attribute__((ext_vector_type(4))) float f32x4;
typedef __attribute__((ext_vector_type(8))) short s16x8;   // 8 bf16 in 4 VGPRs (MFMA A/B frag)
typedef __attribute__((ext_vector_type(4))) short s16x4;
typedef __attribute__((ext_vector_type(4))) int   i32x4;

static __device__ __forceinline__ short f2bf(float f) {
    union { float f; unsigned u; } v; v.f = f;
    unsigned r = (v.u + 0x7FFFu + ((v.u >> 16) & 1u)) >> 16;   // RNE
    return (short)r;
}
static __device__ __forceinline__ float bf2f(short h) {
    union { unsigned u; float f; } v; v.u = ((unsigned)(unsigned short)h) << 16;
    return v.f;
}

// ---------------------------------------------------------------------------
// Kernel 1: projections.  out[b][n][o] = sum_c W[o][c] * x[b][c][n] + bias[o]
// for 3 weight sets (theta->Qb, phi->Kb, g->Vb), bf16 output (B*N, 256).
// MFMA: D = A*B, A = W rows (i=o), B = x^T tile (j=n).  D: lane holds
// out[o=ot*16+4g+r][n=n0+w*16+lo]  -> 4 consecutive o = one 8B store.
// ---------------------------------------------------------------------------
__global__ __launch_bounds__(256) void proj_kernel(
    const float* __restrict__ x,
    const float* __restrict__ tw, const float* __restrict__ tb,
    const float* __restrict__ pw, const float* __restrict__ pb,
    const float* __restrict__ gw, const float* __restrict__ gb,
    short* __restrict__ Qb, short* __restrict__ Kb, short* __restrict__ Vb)
{
    __shared__ char xls[64 * 512];   // xT tile [n(64)][c(256)] bf16, rows XOR-swizzled
    const int blk = blockIdx.x;            // 256 blocks = B * N/64
    const int b   = blk >> 7;
    const int n0  = (blk & 127) << 6;
    const int tid = threadIdx.x;

    // stage x tile (256c x 64n f32) -> transposed bf16
    for (int it = 0; it < 16; ++it) {
        int chunk = it * 256 + tid;                 // 4096 chunks of 4 floats
        int c  = chunk >> 4;
        int n4 = (chunk & 15) << 2;
        const float4 v = *(const float4*)&x[((size_t)b * CC + c) * NN + n0 + n4];
        float vv[4] = {v.x, v.y, v.z, v.w};
        #pragma unroll
        for (int j = 0; j < 4; ++j) {
            int row = n4 + j;
            int addr = (row * 512 + c * 2) ^ ((row & 7) << 4);
            *(short*)(xls + addr) = f2bf(vv[j]);
        }
    }
    __syncthreads();

    const int lane = tid & 63, w = tid >> 6;
    const int lo = lane & 15, g = lane >> 4;

    // B-frags (x^T): row = wave's n-subtile + lo; k-slot = kstep*32 + 8g + e (b128)
    s16x8 bfr[8];
    #pragma unroll
    for (int k = 0; k < 8; ++k) {
        int row = w * 16 + lo;
        int addr = (row * 512 + k * 64 + g * 16) ^ ((row & 7) << 4);
        bfr[k] = *(const s16x8*)(xls + addr);
    }

    const float* Ws[3] = {tw, pw, gw};
    const float* Bs[3] = {tb, pb, gb};
    short*       Os[3] = {Qb, Kb, Vb};
    #pragma unroll
    for (int m = 0; m < 3; ++m) {
        const float* W = Ws[m];
        for (int ot = 0; ot < 16; ++ot) {
            f32x4 acc = {0.f, 0.f, 0.f, 0.f};
            #pragma unroll
            for (int k = 0; k < 8; ++k) {
                const float* wp = &W[(size_t)(ot * 16 + lo) * CC + k * 32 + g * 8];
                float4 wa  = *(const float4*)wp;
                float4 wb2 = *(const float4*)(wp + 4);
                s16x8 afr;
                afr[0]=f2bf(wa.x);  afr[1]=f2bf(wa.y);  afr[2]=f2bf(wa.z);  afr[3]=f2bf(wa.w);
                afr[4]=f2bf(wb2.x); afr[5]=f2bf(wb2.y); afr[6]=f2bf(wb2.z); afr[7]=f2bf(wb2.w);
                acc = __builtin_amdgcn_mfma_f32_16x16x32_bf16(afr, bfr[k], acc, 0, 0, 0);
            }
            const float4 bias = *(const float4*)&Bs[m][ot * 16 + g * 4];
            int n = n0 + w * 16 + lo;
            s16x4 st;
            st[0] = f2bf(acc[0] + bias.x);
            st[1] = f2bf(acc[1] + bias.y);
            st[2] = f2bf(acc[2] + bias.z);
            st[3] = f2bf(acc[3] + bias.w);
            *(s16x4*)&Os[m][((size_t)b * NN + n) * CIc + ot * 16 + g * 4] = st;
        }
    }
}

// ---------------------------------------------------------------------------
// Kernel 2: flash attention, swapped QK^T.  KV-split=2, block = 4 waves,
// wave = 32 q rows (2 Q-tiles).  KVBLK = 64.  LDS: K [64][256] bf16 swizzled,
// Vt [256 d][64 kv] bf16 swizzled.  Writes UNNORMALIZED partials (bf16) and
// (m,l) per q-row per split.
// ---------------------------------------------------------------------------
#define KVB 64

__global__ __launch_bounds__(256, 1) void attn_kernel(
    const short* __restrict__ Qb, const short* __restrict__ Kb, const short* __restrict__ Vb,
    short* __restrict__ part,    // [split][B*N][256] bf16  (lives in d_out)
    float* __restrict__ ml)      // [split][B*N][2]
{
    __shared__ char klds[64 * 512];
    __shared__ char vlds[256 * 128];

    // XCD swizzle: group the 4 (split,batch) combos onto XCD pairs for L2 reuse
    const int s  = blockIdx.x;
    const int lb = (s & 7) * 32 + (s >> 3);       // bijective on [0,256)
    const int split = lb >> 7;
    const int b     = (lb >> 6) & 1;
    const int qblk  = lb & 63;

    const int tid = threadIdx.x, lane = tid & 63, w = tid >> 6;
    const int lo = lane & 15, g = lane >> 4;
    const int q0 = qblk * 128;
    const int kvbase = split * 4096;
    const size_t bN = (size_t)b * NN;

    // Q fragments in registers: [qt][kstep], slot(g,e) = Q[q][k*32+8g+e]
    s16x8 qf[2][8];
    #pragma unroll
    for (int qt = 0; qt < 2; ++qt)
        #pragma unroll
        for (int k = 0; k < 8; ++k)
            qf[qt][k] = *(const s16x8*)&Qb[(bN + q0 + w * 32 + qt * 16 + lo) * CIc + k * 32 + g * 8];

    f32x4 oacc[2][16];
    #pragma unroll
    for (int qt = 0; qt < 2; ++qt)
        #pragma unroll
        for (int d = 0; d < 16; ++d)
            oacc[qt][d] = (f32x4){0.f, 0.f, 0.f, 0.f};
    float mrun[2] = {-1e30f, -1e30f}, lrun[2] = {0.f, 0.f};

    // staging registers (async-stage split: load next tile before compute)
    i32x4 kreg[8], vreg[8];
    #pragma unroll
    for (int ic = 0; ic < 8; ++ic) {
        int chunk = ic * 256 + tid;
        int kv = chunk >> 5, c16 = chunk & 31;
        kreg[ic] = *(const i32x4*)&Kb[(bN + kvbase + kv) * CIc + c16 * 8];
        vreg[ic] = *(const i32x4*)&Vb[(bN + kvbase + kv) * CIc + c16 * 8];
    }

    for (int it = 0; it < 64; ++it) {
        __syncthreads();   // previous tile's compute done
        // write staged regs to LDS
        #pragma unroll
        for (int ic = 0; ic < 8; ++ic) {
            int chunk = ic * 256 + tid;
            int kv = chunk >> 5, c16 = chunk & 31;
            int kaddr = (kv * 512 + c16 * 16) ^ ((kv & 7) << 4);
            *(i32x4*)(klds + kaddr) = kreg[ic];
            union { i32x4 v; short h[8]; } u; u.v = vreg[ic];
            int d8 = c16 * 8;
            #pragma unroll
            for (int j = 0; j < 8; ++j) {
                int jj = (j + (tid & 7)) & 7;       // rotate to spread banks
                int row = d8 + jj;                  // row&7 == jj
                *(short*)(vlds + ((row * 128 + kv * 2) ^ ((row & 7) << 4))) = u.h[jj];
            }
        }
        __syncthreads();
        // issue next tile's global loads (overlap with compute below)
        if (it + 1 < 64) {
            int kvn = kvbase + (it + 1) * KVB;
            #pragma unroll
            for (int ic = 0; ic < 8; ++ic) {
                int chunk = ic * 256 + tid;
                int kv = chunk >> 5, c16 = chunk & 31;
                kreg[ic] = *(const i32x4*)&Kb[(bN + kvn + kv) * CIc + c16 * 8];
                vreg[ic] = *(const i32x4*)&Vb[(bN + kvn + kv) * CIc + c16 * 8];
            }
        }

        // ---- QK^T (swapped): S[kv][q] tiles; lane holds S[kv=kt*16+4g+r][q=lo]
        f32x4 sacc[4][2];
        #pragma unroll
        for (int kt = 0; kt < 4; ++kt)
            #pragma unroll
            for (int qt = 0; qt < 2; ++qt)
                sacc[kt][qt] = (f32x4){0.f, 0.f, 0.f, 0.f};
        #pragma unroll
        for (int k = 0; k < 8; ++k) {
            s16x8 af[4];
            #pragma unroll
            for (int kt = 0; kt < 4; ++kt) {
                int row = kt * 16 + lo;
                int addr = (row * 512 + k * 64 + g * 16) ^ ((row & 7) << 4);
                af[kt] = *(const s16x8*)(klds + addr);
            }
            #pragma unroll
            for (int kt = 0; kt < 4; ++kt)
                #pragma unroll
                for (int qt = 0; qt < 2; ++qt)
                    sacc[kt][qt] = __builtin_amdgcn_mfma_f32_16x16x32_bf16(af[kt], qf[qt][k], sacc[kt][qt], 0, 0, 0);
        }

        // ---- online softmax; lane's q = q0 + w*32 + qt*16 + lo
        s16x8 pa[2][2];
        #pragma unroll
        for (int qt = 0; qt < 2; ++qt) {
            float mx = sacc[0][qt][0];
            #pragma unroll
            for (int kt = 0; kt < 4; ++kt)
                #pragma unroll
                for (int r = 0; r < 4; ++r)
                    mx = fmaxf(mx, sacc[kt][qt][r]);
            mx = fmaxf(mx, __shfl_xor(mx, 16));
            mx = fmaxf(mx, __shfl_xor(mx, 32));
            float mnew = fmaxf(mrun[qt], mx);
            float sum = 0.f;
            #pragma unroll
            for (int kt = 0; kt < 4; ++kt)
                #pragma unroll
                for (int r = 0; r < 4; ++r) {
                    float p = __expf(sacc[kt][qt][r] - mnew);
                    sacc[kt][qt][r] = p;
                    sum += p;
                }
            sum += __shfl_xor(sum, 16);
            sum += __shfl_xor(sum, 32);
            float sc = __expf(mrun[qt] - mnew);
            lrun[qt] = lrun[qt] * sc + sum;
            mrun[qt] = mnew;
            // P -> bf16 A-frags: slot e=4t'+r  <->  kv = s*32 + 16t' + 4g + r
            #pragma unroll
            for (int st2 = 0; st2 < 2; ++st2)
                #pragma unroll
                for (int r = 0; r < 4; ++r) {
                    pa[qt][st2][r]     = f2bf(sacc[st2 * 2 + 0][qt][r]);
                    pa[qt][st2][r + 4] = f2bf(sacc[st2 * 2 + 1][qt][r]);
                }
            // rescale O accumulators (scale for q=...+4g+r lives in lane 4g+r)
            #pragma unroll
            for (int r = 0; r < 4; ++r) {
                float sr = __shfl(sc, g * 4 + r);
                #pragma unroll
                for (int d = 0; d < 16; ++d)
                    oacc[qt][d][r] *= sr;
            }
        }

        // ---- PV: O[q][d] += P * V.  B-frag slot(g,e) = V[kv0+s*32+16(e/4)+4g+(e%4)][dblk*16+lo]
        #pragma unroll
        for (int st2 = 0; st2 < 2; ++st2) {
            #pragma unroll
            for (int d = 0; d < 16; ++d) {
                int row = d * 16 + lo;
                int swz = (row & 7) << 4;
                union { s16x8 v8; s16x4 v4[2]; } vf;
                vf.v4[0] = *(const s16x4*)(vlds + ((row * 128 + st2 * 64 + g * 8) ^ swz));
                vf.v4[1] = *(const s16x4*)(vlds + ((row * 128 + st2 * 64 + g * 8 + 32) ^ swz));
                #pragma unroll
                for (int qt = 0; qt < 2; ++qt)
                    oacc[qt][d] = __builtin_amdgcn_mfma_f32_16x16x32_bf16(pa[qt][st2], vf.v8, oacc[qt][d], 0, 0, 0);
            }
        }
    }

    // epilogue: unnormalized partials + (m,l)
    #pragma unroll
    for (int qt = 0; qt < 2; ++qt) {
        int qg = q0 + w * 32 + qt * 16;
        #pragma unroll
        for (int d = 0; d < 16; ++d)
            #pragma unroll
            for (int r = 0; r < 4; ++r)
                part[((size_t)split * (BB * NN) + bN + qg + g * 4 + r) * CIc + d * 16 + lo]
                    = f2bf(oacc[qt][d][r]);
        if (g == 0) {
            size_t mi = ((size_t)split * (BB * NN) + bN + qg + lo) * 2;
            ml[mi] = mrun[qt]; ml[mi + 1] = lrun[qt];
        }
    }
}

// ---------------------------------------------------------------------------
// Kernel 3: combine the two KV-split partials -> y (B*N, 256) bf16
// ---------------------------------------------------------------------------
__global__ __launch_bounds__(256) void combine_kernel(
    const short* __restrict__ part, const float* __restrict__ ml,
    short* __restrict__ y)
{
    int gid = blockIdx.x * 256 + threadIdx.x;       // 16384 * 32
    int qg = gid >> 5;
    int d8 = (gid & 31) << 3;
    float m0 = ml[(size_t)qg * 2],            l0 = ml[(size_t)qg * 2 + 1];
    float m1 = ml[((size_t)(BB * NN) + qg) * 2], l1 = ml[((size_t)(BB * NN) + qg) * 2 + 1];
    float m  = fmaxf(m0, m1);
    float a0 = __expf(m0 - m), a1 = __expf(m1 - m);
    float inv = 1.f / (a0 * l0 + a1 * l1);
    const s16x8 p0 = *(const s16x8*)&part[(size_t)qg * CIc + d8];
    const s16x8 p1 = *(const s16x8*)&part[((size_t)(BB * NN) + qg) * CIc + d8];
    s16x8 o;
    #pragma unroll
    for (int j = 0; j < 8; ++j)
        o[j] = f2bf((a0 * bf2f(p0[j]) + a1 * bf2f(p1[j])) * inv);
    *(s16x8*)&y[(size_t)qg * CIc + d8] = o;
}

// ---------------------------------------------------------------------------
// Kernel 4: z[b][o][n] = sum_c w_w[o][c]*y[b][n][c] + w_b[o]   (f32 -> d_out)
// A = y rows (i=n), B = w_w rows (j=o).  D: lane holds z[o=ot*16+lo][n=..4g+r]
// -> float4 store over n.
// ---------------------------------------------------------------------------
__global__ __launch_bounds__(256) void zgemm_kernel(
    const short* __restrict__ y,
    const float* __restrict__ ww, const float* __restrict__ wb,
    float* __restrict__ z)
{
    __shared__ char yls[64 * 512];
    const int blk = blockIdx.x;
    const int b   = blk >> 7;
    const int n0  = (blk & 127) << 6;
    const int tid = threadIdx.x;
    #pragma unroll
    for (int ic = 0; ic < 8; ++ic) {
        int chunk = ic * 256 + tid;
        int row = chunk >> 5, c16 = chunk & 31;
        i32x4 v = *(const i32x4*)&y[((size_t)b * NN + n0 + row) * CIc + c16 * 8];
        int addr = (row * 512 + c16 * 16) ^ ((row & 7) << 4);
        *(i32x4*)(yls + addr) = v;
    }
    __syncthreads();
    const int lane = tid & 63, w = tid >> 6, lo = lane & 15, g = lane >> 4;
    s16x8 afr[8];
    #pragma unroll
    for (int k = 0; k < 8; ++k) {
        int row = w * 16 + lo;
        int addr = (row * 512 + k * 64 + g * 16) ^ ((row & 7) << 4);
        afr[k] = *(const s16x8*)(yls + addr);
    }
    for (int ot = 0; ot < 16; ++ot) {
        f32x4 acc = {0.f, 0.f, 0.f, 0.f};
        #pragma unroll
        for (int k = 0; k < 8; ++k) {
            const float* wp = &ww[(size_t)(ot * 16 + lo) * CIc + k * 32 + g * 8];
            float4 wa  = *(const float4*)wp;
            float4 wb2 = *(const float4*)(wp + 4);
            s16x8 bfr;
            bfr[0]=f2bf(wa.x);  bfr[1]=f2bf(wa.y);  bfr[2]=f2bf(wa.z);  bfr[3]=f2bf(wa.w);
            bfr[4]=f2bf(wb2.x); bfr[5]=f2bf(wb2.y); bfr[6]=f2bf(wb2.z); bfr[7]=f2bf(wb2.w);
            acc = __builtin_amdgcn_mfma_f32_16x16x32_bf16(afr[k], bfr, acc, 0, 0, 0);
        }
        float bias = wb[ot * 16 + lo];
        float4 st = {acc[0] + bias, acc[1] + bias, acc[2] + bias, acc[3] + bias};
        *(float4*)&z[((size_t)b * CIc + ot * 16 + lo) * NN + n0 + w * 16 + g * 4] = st;
    }
}

// ---------------------------------------------------------------------------
// Kernel 5: per-channel batch stats over (b, n).  One block per channel.
// ---------------------------------------------------------------------------
__global__ __launch_bounds__(256) void bnstats_kernel(
    const float* __restrict__ z, float* __restrict__ stats)
{
    const int o = blockIdx.x;
    const int tid = threadIdx.x;
    float s = 0.f, s2 = 0.f;
    for (int b = 0; b < BB; ++b) {
        const float* row = &z[((size_t)b * CIc + o) * NN];
        for (int i = tid * 4; i < NN; i += 1024) {
            float4 v = *(const float4*)&row[i];
            s  += v.x + v.y + v.z + v.w;
            s2 += v.x * v.x + v.y * v.y + v.z * v.z + v.w * v.w;
        }
    }
    #pragma unroll
    for (int off = 1; off < 64; off <<= 1) {
        s  += __shfl_xor(s, off);
        s2 += __shfl_xor(s2, off);
    }
    __shared__ float rs[8];
    if ((tid & 63) == 0) { rs[tid >> 6] = s; rs[4 + (tid >> 6)] = s2; }
    __syncthreads();
    if (tid == 0) {
        float S = rs[0] + rs[1] + rs[2] + rs[3];
        float S2 = rs[4] + rs[5] + rs[6] + rs[7];
        float mean = S / (float)(BB * NN);
        float var  = S2 / (float)(BB * NN) - mean * mean;
        stats[o * 2]     = mean;
        stats[o * 2 + 1] = rsqrtf(var + 1e-5f);
    }
}

// ---------------------------------------------------------------------------
// Kernel 6: in-place BN apply on d_out
// ---------------------------------------------------------------------------
__global__ __launch_bounds__(256) void bnapply_kernel(
    float* __restrict__ z, const float* __restrict__ stats,
    const float* __restrict__ gamma, const float* __restrict__ beta)
{
    int gid = blockIdx.x * 256 + threadIdx.x;
    int idx4 = gid * 4;
    int o = (idx4 >> 13) & 255;
    float mean = stats[o * 2], rs = stats[o * 2 + 1];
    float ga = gamma[o], be = beta[o];
    float4 v = *(const float4*)&z[idx4];
    v.x = (v.x - mean) * rs * ga + be;
    v.y = (v.y - mean) * rs * ga + be;
    v.z = (v.z - mean) * rs * ga + be;
    v.w = (v.w - mean) * rs * ga + be;
    *(float4*)&z[idx4] = v;
}

// ---------------------------------------------------------------------------
extern "C" void kernel_launch(void* const* d_in, const int* in_sizes, int n_in,
                              void* d_out, int out_size, void* d_ws, size_t ws_size,
                              hipStream_t stream) {
    const float* x    = (const float*)d_in[0];
    const float* g_w  = (const float*)d_in[1];
    const float* g_b  = (const float*)d_in[2];
    const float* th_w = (const float*)d_in[3];
    const float* th_b = (const float*)d_in[4];
    const float* ph_w = (const float*)d_in[5];
    const float* ph_b = (const float*)d_in[6];
    const float* w_w  = (const float*)d_in[7];
    const float* w_b  = (const float*)d_in[8];
    const float* bn_g = (const float*)d_in[9];
    const float* bn_b = (const float*)d_in[10];

    char* ws = (char*)d_ws;
    short* Qb   = (short*)ws;                    // 8 MiB; reused as y after attn
    short* Kb   = (short*)(ws + 8388608);
    short* Vb   = (short*)(ws + 16777216);
    float* ml   = (float*)(ws + 25165824);       // 256 KiB
    float* stats= (float*)(ws + 25427968);       // 2 KiB
    short* part = (short*)d_out;                 // both splits' partials fit exactly
    float* z    = (float*)d_out;

    proj_kernel<<<256, 256, 0, stream>>>(x, th_w, th_b, ph_w, ph_b, g_w, g_b, Qb, Kb, Vb);
    attn_kernel<<<256, 256, 0, stream>>>(Qb, Kb, Vb, part, ml);
    combine_kernel<<<2048, 256, 0, stream>>>(part, ml, Qb);
    zgemm_kernel<<<256, 256, 0, stream>>>(Qb, w_w, w_b, z);
    bnstats_kernel<<<256, 256, 0, stream>>>(z, stats);
    bnapply_kernel<<<4096, 256, 0, stream>>>(z, stats, bn_g, bn_b);
}

// Round 3
// 370.174 us; speedup vs baseline: 4.3461x; 4.3461x over previous
//
#include <hip/hip_runtime.h>
#include <hip/hip_bf16.h>
#include <stdint.h>

// Problem constants
#define BB  2
#define CC  256
#define NN  8192
#define CIc 256

typedef __attribute__((ext_vector_type(4)))  float f32x4;
typedef __attribute__((ext_vector_type(16))) float f32x16;
typedef __attribute__((ext_vector_type(8)))  short s16x8;   // 8 bf16 = 4 VGPR
typedef __attribute__((ext_vector_type(4)))  short s16x4;
typedef __attribute__((ext_vector_type(4)))  int   i32x4;

static __device__ __forceinline__ short f2bf(float f) {
    union { float f; unsigned u; } v; v.f = f;
    unsigned r = (v.u + 0x7FFFu + ((v.u >> 16) & 1u)) >> 16;   // RNE
    return (short)r;
}
static __device__ __forceinline__ float bf2f(short h) {
    union { unsigned u; float f; } v; v.u = ((unsigned)(unsigned short)h) << 16;
    return v.f;
}

// async global->LDS, 16B per lane, dest = lds_base + lane*16 (wave-uniform base)
static __device__ __forceinline__ void gload16(const void* g, void* l) {
    __builtin_amdgcn_global_load_lds(
        (const __attribute__((address_space(1))) unsigned int*)g,
        (__attribute__((address_space(3))) unsigned int*)l, 16, 0, 0);
}

// ---------------------------------------------------------------------------
// Kernel 1: projections.
//   theta -> Qb [b][n][c]  (bf16)
//   phi   -> Kb [b][n][c]  (bf16)
//   g     -> VT [b][c][n]  (bf16, TRANSPOSED so attention can stage V^T rows)
// ---------------------------------------------------------------------------
__global__ __launch_bounds__(256) void proj_kernel(
    const float* __restrict__ x,
    const float* __restrict__ tw, const float* __restrict__ tb,
    const float* __restrict__ pw, const float* __restrict__ pb,
    const float* __restrict__ gw, const float* __restrict__ gb,
    short* __restrict__ Qb, short* __restrict__ Kb, short* __restrict__ VT)
{
    __shared__ char xls[64 * 512];   // xT tile [n(64)][c(256)] bf16, XOR-swizzled
    const int blk = blockIdx.x;            // 256 blocks = B * N/64
    const int b   = blk >> 7;
    const int n0  = (blk & 127) << 6;
    const int tid = threadIdx.x;

    for (int it = 0; it < 16; ++it) {
        int chunk = it * 256 + tid;
        int c  = chunk >> 4;
        int n4 = (chunk & 15) << 2;
        const float4 v = *(const float4*)&x[((size_t)b * CC + c) * NN + n0 + n4];
        float vv[4] = {v.x, v.y, v.z, v.w};
        #pragma unroll
        for (int j = 0; j < 4; ++j) {
            int row = n4 + j;
            int addr = (row * 512 + c * 2) ^ ((row & 7) << 4);
            *(short*)(xls + addr) = f2bf(vv[j]);
        }
    }
    __syncthreads();

    const int lane = tid & 63, w = tid >> 6;
    const int lo = lane & 15, g = lane >> 4;

    s16x8 bfr[8];
    #pragma unroll
    for (int k = 0; k < 8; ++k) {
        int row = w * 16 + lo;
        int addr = (row * 512 + k * 64 + g * 16) ^ ((row & 7) << 4);
        bfr[k] = *(const s16x8*)(xls + addr);
    }

    #pragma unroll
    for (int m = 0; m < 3; ++m) {
        const float* W  = (m == 0) ? tw : (m == 1) ? pw : gw;
        const float* Bs = (m == 0) ? tb : (m == 1) ? pb : gb;
        for (int ot = 0; ot < 16; ++ot) {
            f32x4 acc = {0.f, 0.f, 0.f, 0.f};
            #pragma unroll
            for (int k = 0; k < 8; ++k) {
                const float* wp = &W[(size_t)(ot * 16 + lo) * CC + k * 32 + g * 8];
                float4 wa  = *(const float4*)wp;
                float4 wb2 = *(const float4*)(wp + 4);
                s16x8 afr;
                afr[0]=f2bf(wa.x);  afr[1]=f2bf(wa.y);  afr[2]=f2bf(wa.z);  afr[3]=f2bf(wa.w);
                afr[4]=f2bf(wb2.x); afr[5]=f2bf(wb2.y); afr[6]=f2bf(wb2.z); afr[7]=f2bf(wb2.w);
                if (m < 2)
                    acc = __builtin_amdgcn_mfma_f32_16x16x32_bf16(afr, bfr[k], acc, 0, 0, 0);
                else
                    acc = __builtin_amdgcn_mfma_f32_16x16x32_bf16(bfr[k], afr, acc, 0, 0, 0);
            }
            if (m < 2) {
                // D: lane holds out[o=ot*16+4g+r][n=n0+w*16+lo]
                const float4 bias = *(const float4*)&Bs[ot * 16 + g * 4];
                short* O = (m == 0) ? Qb : Kb;
                int n = n0 + w * 16 + lo;
                s16x4 st;
                st[0] = f2bf(acc[0] + bias.x);
                st[1] = f2bf(acc[1] + bias.y);
                st[2] = f2bf(acc[2] + bias.z);
                st[3] = f2bf(acc[3] + bias.w);
                *(s16x4*)&O[((size_t)b * NN + n) * CIc + ot * 16 + g * 4] = st;
            } else {
                // swapped: lane holds out[n=n0+w*16+4g+r][o=ot*16+lo] -> VT[o][n]
                float bias = Bs[ot * 16 + lo];
                s16x4 st;
                st[0] = f2bf(acc[0] + bias);
                st[1] = f2bf(acc[1] + bias);
                st[2] = f2bf(acc[2] + bias);
                st[3] = f2bf(acc[3] + bias);
                *(s16x4*)&VT[((size_t)b * CIc + ot * 16 + lo) * NN + n0 + w * 16 + g * 4] = st;
            }
        }
    }
}

// ---------------------------------------------------------------------------
// Kernel 2: flash attention, 32x32x16 MFMA, swapped QK^T, KV-split.
//   wave = 32 q rows (q = lane&31), KVB = 32, double-buffered LDS,
//   fragment-linear LDS (all ds accesses = base + lane*16, conflict-free),
//   staged via global_load_lds with fragment-order source addressing.
// A/B slot map: row|col=lane&31, k=(lane>>5)*8+e (mirrors the 16x16 map
// validated in round 1).  C/D (HW-verified): col=lane&31,
// row=(reg&3)+8*(reg>>2)+4*(lane>>5).
// Cross-lane ops use __shfl_xor (round-1-validated) -- NO permlane asm.
// ---------------------------------------------------------------------------
template<int SPLIT>
__global__ __launch_bounds__(256, 2) void attn2_kernel(
    const short* __restrict__ Qb, const short* __restrict__ Kb,
    const short* __restrict__ VT,
    short* __restrict__ part,    // [SPLIT][B*N][256] bf16 (unnormalized)
    float* __restrict__ ml)      // [SPLIT][B*N][2]
{
    __shared__ char lds[65536];  // 2 bufs x (K 16KB | V 16KB)
    const int blk   = blockIdx.x;
    const int combo = blk & (2 * SPLIT - 1);      // XCD-affine grouping
    const int split = combo >> 1;
    const int b     = combo & 1;
    const int qblk  = blk / (2 * SPLIT);          // 0..63
    const int tid = threadIdx.x, lane = tid & 63, w = tid >> 6;
    const int l31 = lane & 31, h = lane >> 5;
    const int q   = qblk * 128 + w * 32 + l31;
    const size_t bN = (size_t)b * NN;
    const int kvbase = split * (NN / SPLIT);
    const int NT = (NN / SPLIT) / 32;

    // ---- stage tile 0 (K: insts 0-15, V: insts 16-31; each wave issues 8)
    {
        const int kvt = kvbase;
        #pragma unroll
        for (int j = 0; j < 8; ++j) {
            const int inst = w * 8 + j;
            if (inst < 16) {
                gload16(&Kb[(bN + kvt + l31) * CIc + inst * 16 + h * 8],
                        lds + inst * 1024);
            } else {
                const int i = inst - 16;               // i = kv0idx*8 + dt
                const int kv0 = (i >> 3) * 16, dt = i & 7;
                gload16(&VT[((size_t)b * CIc + dt * 32 + l31) * NN + kvt + kv0 + h * 8],
                        lds + 16384 + i * 1024);
            }
        }
    }

    // ---- Q fragments: qf[ks] = Q[q][ks*16 + h*8 .. +7]
    s16x8 qf[16];
    #pragma unroll
    for (int ks = 0; ks < 16; ++ks)
        qf[ks] = *(const s16x8*)&Qb[(bN + q) * CIc + ks * 16 + h * 8];

    f32x16 acc[8];
    #pragma unroll
    for (int dt = 0; dt < 8; ++dt)
        #pragma unroll
        for (int r = 0; r < 16; ++r) acc[dt][r] = 0.f;
    float m_use = -1e30f, l_run = 0.f;

    for (int t = 0; t < NT; ++t) {
        __syncthreads();   // tile t staged (compiler drains vmcnt before barrier)
        const char* cbuf = lds + (t & 1) * 32768;
        if (t + 1 < NT) {
            char* nbuf = lds + ((t + 1) & 1) * 32768;
            const int kvt = kvbase + (t + 1) * 32;
            #pragma unroll
            for (int j = 0; j < 8; ++j) {
                const int inst = w * 8 + j;
                if (inst < 16) {
                    gload16(&Kb[(bN + kvt + l31) * CIc + inst * 16 + h * 8],
                            nbuf + inst * 1024);
                } else {
                    const int i = inst - 16;
                    const int kv0 = (i >> 3) * 16, dt = i & 7;
                    gload16(&VT[((size_t)b * CIc + dt * 32 + l31) * NN + kvt + kv0 + h * 8],
                            nbuf + 16384 + i * 1024);
                }
            }
        }

        // ---- QK^T: S[kv=32][q=32]; lane: q=l31, kv(reg)=(reg&3)+8*(reg>>2)+4h
        f32x16 sacc;
        #pragma unroll
        for (int r = 0; r < 16; ++r) sacc[r] = 0.f;
        #pragma unroll
        for (int ks = 0; ks < 16; ++ks) {
            s16x8 kf = *(const s16x8*)(cbuf + ks * 1024 + lane * 16);
            sacc = __builtin_amdgcn_mfma_f32_32x32x16_bf16(kf, qf[ks], sacc, 0, 0, 0);
        }

        // ---- online softmax (lane-local; partner lane^32 has same q)
        float tmax = fmaxf(sacc[0], sacc[1]);
        #pragma unroll
        for (int r = 2; r < 16; ++r) tmax = fmaxf(tmax, sacc[r]);
        tmax = fmaxf(tmax, __shfl_xor(tmax, 32));
        if (!__all(tmax - m_use <= 8.0f)) {       // defer-max THR=8
            float mnew = fmaxf(m_use, tmax);
            float sc = __expf(m_use - mnew);
            l_run *= sc;
            #pragma unroll
            for (int dt = 0; dt < 8; ++dt)
                #pragma unroll
                for (int r = 0; r < 16; ++r) acc[dt][r] *= sc;
            m_use = mnew;
        }
        float sum = 0.f;
        #pragma unroll
        for (int r = 0; r < 16; ++r) {
            float p = __expf(sacc[r] - m_use);
            sacc[r] = p; sum += p;
        }
        sum += __shfl_xor(sum, 32);
        l_run += sum;

        // ---- P -> bf16 B-frags, slot k = h*8+e.  Own lane holds kv
        // (r&3)+8*(r>>2)+4h; partner half comes via shfl_xor(.,32).
        union { int wd[4]; s16x8 v; } f0, f1;
        {
            int w01, w23, w45, w67;
            asm("v_cvt_pk_bf16_f32 %0, %1, %2" : "=v"(w01) : "v"(sacc[0]), "v"(sacc[1]));
            asm("v_cvt_pk_bf16_f32 %0, %1, %2" : "=v"(w23) : "v"(sacc[2]), "v"(sacc[3]));
            asm("v_cvt_pk_bf16_f32 %0, %1, %2" : "=v"(w45) : "v"(sacc[4]), "v"(sacc[5]));
            asm("v_cvt_pk_bf16_f32 %0, %1, %2" : "=v"(w67) : "v"(sacc[6]), "v"(sacc[7]));
            int x01 = __shfl_xor(w01, 32), x23 = __shfl_xor(w23, 32);
            int x45 = __shfl_xor(w45, 32), x67 = __shfl_xor(w67, 32);
            f0.wd[0] = h ? x45 : w01;     // e0,e1 : kv h*8+0,1
            f0.wd[1] = h ? x67 : w23;     // e2,e3 : kv h*8+2,3
            f0.wd[2] = h ? w45 : x01;     // e4,e5 : kv h*8+4,5
            f0.wd[3] = h ? w67 : x23;     // e6,e7 : kv h*8+6,7
        }
        {
            int w01, w23, w45, w67;
            asm("v_cvt_pk_bf16_f32 %0, %1, %2" : "=v"(w01) : "v"(sacc[8]),  "v"(sacc[9]));
            asm("v_cvt_pk_bf16_f32 %0, %1, %2" : "=v"(w23) : "v"(sacc[10]), "v"(sacc[11]));
            asm("v_cvt_pk_bf16_f32 %0, %1, %2" : "=v"(w45) : "v"(sacc[12]), "v"(sacc[13]));
            asm("v_cvt_pk_bf16_f32 %0, %1, %2" : "=v"(w67) : "v"(sacc[14]), "v"(sacc[15]));
            int x01 = __shfl_xor(w01, 32), x23 = __shfl_xor(w23, 32);
            int x45 = __shfl_xor(w45, 32), x67 = __shfl_xor(w67, 32);
            f1.wd[0] = h ? x45 : w01;
            f1.wd[1] = h ? x67 : w23;
            f1.wd[2] = h ? w45 : x01;
            f1.wd[3] = h ? w67 : x23;
        }

        // ---- PV: O^T[d][q] += V^T-frag x P-frag
        const char* vbuf = cbuf + 16384;
        #pragma unroll
        for (int dt = 0; dt < 8; ++dt) {
            s16x8 v0 = *(const s16x8*)(vbuf + (dt) * 1024 + lane * 16);
            s16x8 v1 = *(const s16x8*)(vbuf + (8 + dt) * 1024 + lane * 16);
            acc[dt] = __builtin_amdgcn_mfma_f32_32x32x16_bf16(v0, f0.v, acc[dt], 0, 0, 0);
            acc[dt] = __builtin_amdgcn_mfma_f32_32x32x16_bf16(v1, f1.v, acc[dt], 0, 0, 0);
        }
    }

    // ---- epilogue: unnormalized partial + (m,l).  d = dt*32 + rg*8 + 4h + 0..3
    const size_t pbase = ((size_t)split * (BB * NN) + bN + q) * CIc;
    #pragma unroll
    for (int dt = 0; dt < 8; ++dt)
        #pragma unroll
        for (int rg = 0; rg < 4; ++rg) {
            s16x4 st;
            st[0] = f2bf(acc[dt][rg * 4 + 0]);
            st[1] = f2bf(acc[dt][rg * 4 + 1]);
            st[2] = f2bf(acc[dt][rg * 4 + 2]);
            st[3] = f2bf(acc[dt][rg * 4 + 3]);
            *(s16x4*)&part[pbase + dt * 32 + rg * 8 + h * 4] = st;
        }
    if (h == 0) {
        size_t mi = ((size_t)split * (BB * NN) + bN + q) * 2;
        ml[mi] = m_use; ml[mi + 1] = l_run;
    }
}

// ---------------------------------------------------------------------------
// Kernel 3: combine KV-split partials -> y [b][n][c] bf16
// ---------------------------------------------------------------------------
template<int SPLIT>
__global__ __launch_bounds__(256) void combine2_kernel(
    const short* __restrict__ part, const float* __restrict__ ml,
    short* __restrict__ y)
{
    int gid = blockIdx.x * 256 + threadIdx.x;     // 16384 * 32
    int qg = gid >> 5;
    int c8 = (gid & 31) << 3;
    float mm[SPLIT], ll[SPLIT];
    float m = -1e30f;
    #pragma unroll
    for (int s = 0; s < SPLIT; ++s) {
        mm[s] = ml[((size_t)s * (BB * NN) + qg) * 2];
        ll[s] = ml[((size_t)s * (BB * NN) + qg) * 2 + 1];
        m = fmaxf(m, mm[s]);
    }
    float den = 0.f, a[SPLIT];
    #pragma unroll
    for (int s = 0; s < SPLIT; ++s) { a[s] = __expf(mm[s] - m); den += a[s] * ll[s]; }
    float o[8];
    #pragma unroll
    for (int j = 0; j < 8; ++j) o[j] = 0.f;
    #pragma unroll
    for (int s = 0; s < SPLIT; ++s) {
        s16x8 p = *(const s16x8*)&part[((size_t)s * (BB * NN) + qg) * CIc + c8];
        #pragma unroll
        for (int j = 0; j < 8; ++j) o[j] += a[s] * bf2f(p[j]);
    }
    float inv = 1.f / den;
    s16x8 st;
    #pragma unroll
    for (int j = 0; j < 8; ++j) st[j] = f2bf(o[j] * inv);
    *(s16x8*)&y[(size_t)qg * CIc + c8] = st;
}

// ---------------------------------------------------------------------------
// Kernel 4: z[b][o][n] = sum_c w_w[o][c]*y[b][n][c] + w_b[o]   (f32 -> d_out)
// ---------------------------------------------------------------------------
__global__ __launch_bounds__(256) void zgemm_kernel(
    const short* __restrict__ y,
    const float* __restrict__ ww, const float* __restrict__ wb,
    float* __restrict__ z)
{
    __shared__ char yls[64 * 512];
    const int blk = blockIdx.x;
    const int b   = blk >> 7;
    const int n0  = (blk & 127) << 6;
    const int tid = threadIdx.x;
    #pragma unroll
    for (int ic = 0; ic < 8; ++ic) {
        int chunk = ic * 256 + tid;
        int row = chunk >> 5, c16 = chunk & 31;
        i32x4 v = *(const i32x4*)&y[((size_t)b * NN + n0 + row) * CIc + c16 * 8];
        int addr = (row * 512 + c16 * 16) ^ ((row & 7) << 4);
        *(i32x4*)(yls + addr) = v;
    }
    __syncthreads();
    const int lane = tid & 63, w = tid >> 6, lo = lane & 15, g = lane >> 4;
    s16x8 afr[8];
    #pragma unroll
    for (int k = 0; k < 8; ++k) {
        int row = w * 16 + lo;
        int addr = (row * 512 + k * 64 + g * 16) ^ ((row & 7) << 4);
        afr[k] = *(const s16x8*)(yls + addr);
    }
    for (int ot = 0; ot < 16; ++ot) {
        f32x4 acc = {0.f, 0.f, 0.f, 0.f};
        #pragma unroll
        for (int k = 0; k < 8; ++k) {
            const float* wp = &ww[(size_t)(ot * 16 + lo) * CIc + k * 32 + g * 8];
            float4 wa  = *(const float4*)wp;
            float4 wb2 = *(const float4*)(wp + 4);
            s16x8 bfr;
            bfr[0]=f2bf(wa.x);  bfr[1]=f2bf(wa.y);  bfr[2]=f2bf(wa.z);  bfr[3]=f2bf(wa.w);
            bfr[4]=f2bf(wb2.x); bfr[5]=f2bf(wb2.y); bfr[6]=f2bf(wb2.z); bfr[7]=f2bf(wb2.w);
            acc = __builtin_amdgcn_mfma_f32_16x16x32_bf16(afr[k], bfr, acc, 0, 0, 0);
        }
        float bias = wb[ot * 16 + lo];
        float4 st = {acc[0] + bias, acc[1] + bias, acc[2] + bias, acc[3] + bias};
        *(float4*)&z[((size_t)b * CIc + ot * 16 + lo) * NN + n0 + w * 16 + g * 4] = st;
    }
}

// ---------------------------------------------------------------------------
// Kernel 5: per-channel batch stats (mean, rsqrt(var+eps)); 1 block/channel
// ---------------------------------------------------------------------------
__global__ __launch_bounds__(256) void bnstats_kernel(
    const float* __restrict__ z, float* __restrict__ stats)
{
    const int o = blockIdx.x;
    const int tid = threadIdx.x;
    float s = 0.f, s2 = 0.f;
    for (int b = 0; b < BB; ++b) {
        const float* row = &z[((size_t)b * CIc + o) * NN];
        for (int i = tid * 4; i < NN; i += 1024) {
            float4 v = *(const float4*)&row[i];
            s  += v.x + v.y + v.z + v.w;
            s2 += v.x * v.x + v.y * v.y + v.z * v.z + v.w * v.w;
        }
    }
    #pragma unroll
    for (int off = 1; off < 64; off <<= 1) {
        s  += __shfl_xor(s, off);
        s2 += __shfl_xor(s2, off);
    }
    __shared__ float rs[8];
    if ((tid & 63) == 0) { rs[tid >> 6] = s; rs[4 + (tid >> 6)] = s2; }
    __syncthreads();
    if (tid == 0) {
        float S  = rs[0] + rs[1] + rs[2] + rs[3];
        float S2 = rs[4] + rs[5] + rs[6] + rs[7];
        float mean = S / (float)(BB * NN);
        float var  = S2 / (float)(BB * NN) - mean * mean;
        stats[o * 2]     = mean;
        stats[o * 2 + 1] = rsqrtf(var + 1e-5f);
    }
}

// ---------------------------------------------------------------------------
// Kernel 6: in-place BN apply on d_out
// ---------------------------------------------------------------------------
__global__ __launch_bounds__(256) void bnapply_kernel(
    float* __restrict__ z, const float* __restrict__ stats,
    const float* __restrict__ gamma, const float* __restrict__ beta)
{
    int gid = blockIdx.x * 256 + threadIdx.x;
    int idx4 = gid * 4;
    int o = (idx4 >> 13) & 255;
    float mean = stats[o * 2], rs = stats[o * 2 + 1];
    float ga = gamma[o], be = beta[o];
    float4 v = *(const float4*)&z[idx4];
    v.x = (v.x - mean) * rs * ga + be;
    v.y = (v.y - mean) * rs * ga + be;
    v.z = (v.z - mean) * rs * ga + be;
    v.w = (v.w - mean) * rs * ga + be;
    *(float4*)&z[idx4] = v;
}

// ---------------------------------------------------------------------------
extern "C" void kernel_launch(void* const* d_in, const int* in_sizes, int n_in,
                              void* d_out, int out_size, void* d_ws, size_t ws_size,
                              hipStream_t stream) {
    const float* x    = (const float*)d_in[0];
    const float* g_w  = (const float*)d_in[1];
    const float* g_b  = (const float*)d_in[2];
    const float* th_w = (const float*)d_in[3];
    const float* th_b = (const float*)d_in[4];
    const float* ph_w = (const float*)d_in[5];
    const float* ph_b = (const float*)d_in[6];
    const float* w_w  = (const float*)d_in[7];
    const float* w_b  = (const float*)d_in[8];
    const float* bn_g = (const float*)d_in[9];
    const float* bn_b = (const float*)d_in[10];

    char* ws = (char*)d_ws;
    short* Qb    = (short*)ws;                         // 8 MiB (reused as y)
    short* Kb    = (short*)(ws + 8  * 1048576);        // 8 MiB
    short* VT    = (short*)(ws + 16 * 1048576);        // 8 MiB
    float* ml    = (float*)(ws + 24 * 1048576);        // <= 512 KiB
    float* stats = (float*)(ws + 24 * 1048576 + 524288);
    float* z     = (float*)d_out;

    const size_t need4 = (size_t)26 * 1048576 + (size_t)4 * BB * NN * CIc * 2;
    const bool  big    = ws_size >= need4;

    proj_kernel<<<256, 256, 0, stream>>>(x, th_w, th_b, ph_w, ph_b, g_w, g_b, Qb, Kb, VT);

    if (big) {
        short* part = (short*)(ws + 26 * 1048576);     // 32 MiB
        attn2_kernel<4><<<512, 256, 0, stream>>>(Qb, Kb, VT, part, ml);
        combine2_kernel<4><<<2048, 256, 0, stream>>>(part, ml, Qb);
    } else {
        short* part = (short*)d_out;                   // 2 splits fit d_out exactly
        attn2_kernel<2><<<256, 256, 0, stream>>>(Qb, Kb, VT, part, ml);
        combine2_kernel<2><<<2048, 256, 0, stream>>>(part, ml, Qb);
    }

    zgemm_kernel<<<256, 256, 0, stream>>>(Qb, w_w, w_b, z);
    bnstats_kernel<<<256, 256, 0, stream>>>(z, stats);
    bnapply_kernel<<<4096, 256, 0, stream>>>(z, stats, bn_g, bn_b);
}

// Round 4
// 314.487 us; speedup vs baseline: 5.1156x; 1.1771x over previous
//
#include <hip/hip_runtime.h>
#include <hip/hip_bf16.h>
#include <stdint.h>

// Problem constants
#define BB  2
#define CC  256
#define NN  8192
#define CIc 256

typedef __attribute__((ext_vector_type(4)))  float f32x4;
typedef __attribute__((ext_vector_type(16))) float f32x16;
typedef __attribute__((ext_vector_type(8)))  short s16x8;   // 8 bf16 = 4 VGPR
typedef __attribute__((ext_vector_type(4)))  short s16x4;
typedef __attribute__((ext_vector_type(4)))  int   i32x4;

static __device__ __forceinline__ short f2bf(float f) {
    union { float f; unsigned u; } v; v.f = f;
    unsigned r = (v.u + 0x7FFFu + ((v.u >> 16) & 1u)) >> 16;   // RNE
    return (short)r;
}
static __device__ __forceinline__ float bf2f(short h) {
    union { unsigned u; float f; } v; v.u = ((unsigned)(unsigned short)h) << 16;
    return v.f;
}

// async global->LDS, 16B per lane, dest = lds_base + lane*16 (wave-uniform base)
static __device__ __forceinline__ void gload16(const void* g, void* l) {
    __builtin_amdgcn_global_load_lds(
        (const __attribute__((address_space(1))) unsigned int*)g,
        (__attribute__((address_space(3))) unsigned int*)l, 16, 0, 0);
}

// ---------------------------------------------------------------------------
// Kernel 0: pack the 4 weight matrices (theta, phi, g, w) f32[256][256] into
// bf16 MFMA-fragment order:  Wf[m][ot][ks][lane][8e] =
//   W[ot*16 + (lane&15)][ks*32 + (lane>>4)*8 + e]
// Serves both A-operand (i=row) and B-operand (j=row) roles of 16x16x32.
// ---------------------------------------------------------------------------
__global__ __launch_bounds__(256) void pack_kernel(
    const float* __restrict__ tw, const float* __restrict__ pw,
    const float* __restrict__ gw, const float* __restrict__ ww,
    short* __restrict__ Wf)
{
    int gid  = blockIdx.x * 256 + threadIdx.x;   // 32768 threads
    int lane = gid & 63;
    int grp  = gid >> 6;                          // [0,512): m*128 + ot*8 + ks
    int ks = grp & 7, ot = (grp >> 3) & 15, m = grp >> 7;
    const float* W = (m == 0) ? tw : (m == 1) ? pw : (m == 2) ? gw : ww;
    const float* p = &W[(size_t)(ot * 16 + (lane & 15)) * 256 + ks * 32 + (lane >> 4) * 8];
    float4 a = *(const float4*)p, c = *(const float4*)(p + 4);
    s16x8 o;
    o[0] = f2bf(a.x); o[1] = f2bf(a.y); o[2] = f2bf(a.z); o[3] = f2bf(a.w);
    o[4] = f2bf(c.x); o[5] = f2bf(c.y); o[6] = f2bf(c.z); o[7] = f2bf(c.w);
    *(s16x8*)&Wf[(size_t)gid * 8] = o;
}

// ---------------------------------------------------------------------------
// Kernel 1: projections.  grid = 3 (matrix) x B x N/64.  One matrix per block.
//   m=0 theta -> Qb [b][n][c] row-major bf16
//   m=1 phi   -> Kf fragment-packed: Kf[b][t][ks(16)][L(64)][8] =
//                K[t*32 + (L&31)][ks*16 + (L>>5)*8 + e]
//   m=2 g     -> Vf fragment-packed: Vf[b][t][i(16)][L(64)][8] =
//                V[t*32 + (i>>3)*16 + (L>>5)*8 + e][(i&7)*32 + (L&31)]
// ---------------------------------------------------------------------------
__global__ __launch_bounds__(256) void proj_kernel(
    const float* __restrict__ x, const short* __restrict__ Wf,
    const float* __restrict__ tb, const float* __restrict__ pb,
    const float* __restrict__ gb,
    short* __restrict__ Qb, short* __restrict__ Kf, short* __restrict__ Vf)
{
    __shared__ char xls[64 * 512];   // xT tile [n(64)][c(256)] bf16, XOR-swizzled
    const int blk = blockIdx.x;            // 768 blocks
    const int m   = blk % 3;
    const int r2  = blk / 3;
    const int b   = r2 >> 7;
    const int n0  = (r2 & 127) << 6;
    const int tid = threadIdx.x;

    for (int it = 0; it < 16; ++it) {
        int chunk = it * 256 + tid;
        int c  = chunk >> 4;
        int n4 = (chunk & 15) << 2;
        const float4 v = *(const float4*)&x[((size_t)b * CC + c) * NN + n0 + n4];
        float vv[4] = {v.x, v.y, v.z, v.w};
        #pragma unroll
        for (int j = 0; j < 4; ++j) {
            int row = n4 + j;
            int addr = row * 512 + ((c * 2) ^ ((row & 31) << 4));
            *(short*)(xls + addr) = f2bf(vv[j]);
        }
    }
    __syncthreads();

    const int lane = tid & 63, w = tid >> 6;
    const int lo = lane & 15, g = lane >> 4;

    s16x8 bfr[8];
    #pragma unroll
    for (int k = 0; k < 8; ++k) {
        int row = w * 16 + lo;
        int addr = row * 512 + ((k * 64 + g * 16) ^ ((row & 31) << 4));
        bfr[k] = *(const s16x8*)(xls + addr);
    }

    const float* bias = (m == 0) ? tb : (m == 1) ? pb : gb;
    const size_t wfm = (size_t)m * 16 * 8 * 512;

    for (int ot = 0; ot < 16; ++ot) {
        s16x8 afr[8];
        #pragma unroll
        for (int k = 0; k < 8; ++k)
            afr[k] = *(const s16x8*)&Wf[wfm + (size_t)(ot * 8 + k) * 512 + lane * 8];
        f32x4 acc = {0.f, 0.f, 0.f, 0.f};
        if (m < 2) {
            #pragma unroll
            for (int k = 0; k < 8; ++k)
                acc = __builtin_amdgcn_mfma_f32_16x16x32_bf16(afr[k], bfr[k], acc, 0, 0, 0);
        } else {
            #pragma unroll
            for (int k = 0; k < 8; ++k)
                acc = __builtin_amdgcn_mfma_f32_16x16x32_bf16(bfr[k], afr[k], acc, 0, 0, 0);
        }

        if (m == 0) {
            // lane holds out[o=ot*16+4g+r][n=n0+w*16+lo] -> Qb row-major
            const float4 bi = *(const float4*)&bias[ot * 16 + g * 4];
            int n = n0 + w * 16 + lo;
            s16x4 st;
            st[0] = f2bf(acc[0] + bi.x);
            st[1] = f2bf(acc[1] + bi.y);
            st[2] = f2bf(acc[2] + bi.z);
            st[3] = f2bf(acc[3] + bi.w);
            *(s16x4*)&Qb[((size_t)b * NN + n) * CIc + ot * 16 + g * 4] = st;
        } else if (m == 1) {
            // lane holds K[c=ot*16+g*4+r][n=n0+w*16+lo] (c is the "o" axis)
            const float4 bi = *(const float4*)&bias[ot * 16 + g * 4];
            int n = n0 + w * 16 + lo;
            s16x4 st;
            st[0] = f2bf(acc[0] + bi.x);
            st[1] = f2bf(acc[1] + bi.y);
            st[2] = f2bf(acc[2] + bi.z);
            st[3] = f2bf(acc[3] + bi.w);
            size_t a = ((((size_t)b * 256 + (n >> 5)) * 16 + ot) * 64
                        + (n & 31) + 32 * (g >> 1)) * 8 + (g & 1) * 4;
            *(s16x4*)&Kf[a] = st;
        } else {
            // swapped: lane holds V[n=n0+w*16+g*4+r][o=ot*16+lo]
            int nb = n0 + w * 16 + g * 4;
            int o  = ot * 16 + lo;
            float bo = bias[o];
            s16x4 st;
            st[0] = f2bf(acc[0] + bo);
            st[1] = f2bf(acc[1] + bo);
            st[2] = f2bf(acc[2] + bo);
            st[3] = f2bf(acc[3] + bo);
            size_t a = ((((size_t)b * 256 + (nb >> 5)) * 16 + (w & 1) * 8 + (ot >> 1)) * 64
                        + (ot & 1) * 16 + lo + 32 * (g >> 1)) * 8 + (g & 1) * 4;
            *(s16x4*)&Vf[a] = st;
        }
    }
}

// ---------------------------------------------------------------------------
// Kernel 2: flash attention, 32x32x16 MFMA, swapped QK^T, KV-split.
//   wave = 32 q rows, block = 4 waves (128 q).  K in LDS (double-buffered,
//   fragment-linear, staged via global_load_lds from packed Kf -> coalesced
//   1KB per instruction).  V read directly from packed Vf global (L1-resident,
//   shared by all co-resident waves of the same (split,b) combo).
// ---------------------------------------------------------------------------
template<int SPLIT>
__global__ __launch_bounds__(256, 2) void attn2_kernel(
    const short* __restrict__ Qb, const short* __restrict__ Kf,
    const short* __restrict__ Vf,
    short* __restrict__ part,    // [SPLIT][B*N][256] bf16 (unnormalized)
    float* __restrict__ ml)      // [SPLIT][B*N][2]
{
    __shared__ char lds[32768];  // 2 x 16KB K tiles
    const int blk   = blockIdx.x;
    const int combo = blk & (2 * SPLIT - 1);      // XCD-affine grouping
    const int split = combo >> 1;
    const int b     = combo & 1;
    const int qblk  = blk / (2 * SPLIT);          // 0..63
    const int tid = threadIdx.x, lane = tid & 63, w = tid >> 6;
    const int l31 = lane & 31, h = lane >> 5;
    const int q   = qblk * 128 + w * 32 + l31;
    const size_t bN = (size_t)b * NN;
    const int tgbase = (split * (NN / SPLIT)) >> 5;
    const int NT = (NN / SPLIT) / 32;

    // ---- stage K tile 0 (16 insts; each wave issues 4)
    #pragma unroll
    for (int j = 0; j < 4; ++j) {
        const int inst = w * 4 + j;
        gload16(&Kf[(((size_t)(b * 256 + tgbase) * 16) + inst) * 512 + lane * 8],
                lds + inst * 1024);
    }

    // ---- Q fragments: qf[ks] = Q[q][ks*16 + h*8 .. +7]
    s16x8 qf[16];
    #pragma unroll
    for (int ks = 0; ks < 16; ++ks)
        qf[ks] = *(const s16x8*)&Qb[(bN + q) * CIc + ks * 16 + h * 8];

    f32x16 acc[8];
    #pragma unroll
    for (int dt = 0; dt < 8; ++dt)
        #pragma unroll
        for (int r = 0; r < 16; ++r) acc[dt][r] = 0.f;
    float m_use = -1e30f, l_run = 0.f;

    for (int t = 0; t < NT; ++t) {
        __syncthreads();   // tile t staged
        const char* cbuf = lds + (t & 1) * 16384;
        const int tg = tgbase + t;
        if (t + 1 < NT) {
            char* nbuf = lds + ((t + 1) & 1) * 16384;
            #pragma unroll
            for (int j = 0; j < 4; ++j) {
                const int inst = w * 4 + j;
                gload16(&Kf[(((size_t)(b * 256 + tg + 1) * 16) + inst) * 512 + lane * 8],
                        nbuf + inst * 1024);
            }
        }

        // ---- QK^T: S[kv=32][q=32]; lane: q=l31, kv(reg)=(reg&3)+8*(reg>>2)+4h
        f32x16 sacc;
        #pragma unroll
        for (int r = 0; r < 16; ++r) sacc[r] = 0.f;
        #pragma unroll
        for (int ks = 0; ks < 16; ++ks) {
            s16x8 kf = *(const s16x8*)(cbuf + ks * 1024 + lane * 16);
            sacc = __builtin_amdgcn_mfma_f32_32x32x16_bf16(kf, qf[ks], sacc, 0, 0, 0);
        }

        // ---- online softmax (lane-local; partner lane^32 has same q)
        float tmax = fmaxf(sacc[0], sacc[1]);
        #pragma unroll
        for (int r = 2; r < 16; ++r) tmax = fmaxf(tmax, sacc[r]);
        tmax = fmaxf(tmax, __shfl_xor(tmax, 32));
        if (!__all(tmax - m_use <= 8.0f)) {       // defer-max THR=8
            float mnew = fmaxf(m_use, tmax);
            float sc = __expf(m_use - mnew);
            l_run *= sc;
            #pragma unroll
            for (int dt = 0; dt < 8; ++dt)
                #pragma unroll
                for (int r = 0; r < 16; ++r) acc[dt][r] *= sc;
            m_use = mnew;
        }
        float sum = 0.f;
        #pragma unroll
        for (int r = 0; r < 16; ++r) {
            float p = __expf(sacc[r] - m_use);
            sacc[r] = p; sum += p;
        }
        sum += __shfl_xor(sum, 32);
        l_run += sum;

        // ---- P -> bf16 B-frags, slot k = h*8+e (shfl_xor cross-half)
        union { int wd[4]; s16x8 v; } f0, f1;
        {
            int w01, w23, w45, w67;
            asm("v_cvt_pk_bf16_f32 %0, %1, %2" : "=v"(w01) : "v"(sacc[0]), "v"(sacc[1]));
            asm("v_cvt_pk_bf16_f32 %0, %1, %2" : "=v"(w23) : "v"(sacc[2]), "v"(sacc[3]));
            asm("v_cvt_pk_bf16_f32 %0, %1, %2" : "=v"(w45) : "v"(sacc[4]), "v"(sacc[5]));
            asm("v_cvt_pk_bf16_f32 %0, %1, %2" : "=v"(w67) : "v"(sacc[6]), "v"(sacc[7]));
            int x01 = __shfl_xor(w01, 32), x23 = __shfl_xor(w23, 32);
            int x45 = __shfl_xor(w45, 32), x67 = __shfl_xor(w67, 32);
            f0.wd[0] = h ? x45 : w01;
            f0.wd[1] = h ? x67 : w23;
            f0.wd[2] = h ? w45 : x01;
            f0.wd[3] = h ? w67 : x23;
        }
        {
            int w01, w23, w45, w67;
            asm("v_cvt_pk_bf16_f32 %0, %1, %2" : "=v"(w01) : "v"(sacc[8]),  "v"(sacc[9]));
            asm("v_cvt_pk_bf16_f32 %0, %1, %2" : "=v"(w23) : "v"(sacc[10]), "v"(sacc[11]));
            asm("v_cvt_pk_bf16_f32 %0, %1, %2" : "=v"(w45) : "v"(sacc[12]), "v"(sacc[13]));
            asm("v_cvt_pk_bf16_f32 %0, %1, %2" : "=v"(w67) : "v"(sacc[14]), "v"(sacc[15]));
            int x01 = __shfl_xor(w01, 32), x23 = __shfl_xor(w23, 32);
            int x45 = __shfl_xor(w45, 32), x67 = __shfl_xor(w67, 32);
            f1.wd[0] = h ? x45 : w01;
            f1.wd[1] = h ? x67 : w23;
            f1.wd[2] = h ? w45 : x01;
            f1.wd[3] = h ? w67 : x23;
        }

        // ---- PV: O^T[d][q] += V^T-frag x P-frag; V frags direct from global
        const size_t vbase = (size_t)(b * 256 + tg) * 16 * 512 + lane * 8;
        #pragma unroll
        for (int dt = 0; dt < 8; ++dt) {
            s16x8 v0 = *(const s16x8*)&Vf[vbase + (size_t)dt * 512];
            s16x8 v1 = *(const s16x8*)&Vf[vbase + (size_t)(8 + dt) * 512];
            acc[dt] = __builtin_amdgcn_mfma_f32_32x32x16_bf16(v0, f0.v, acc[dt], 0, 0, 0);
            acc[dt] = __builtin_amdgcn_mfma_f32_32x32x16_bf16(v1, f1.v, acc[dt], 0, 0, 0);
        }
    }

    // ---- epilogue: unnormalized partial + (m,l).  d = dt*32 + rg*8 + 4h + 0..3
    const size_t pbase = ((size_t)split * (BB * NN) + bN + q) * CIc;
    #pragma unroll
    for (int dt = 0; dt < 8; ++dt)
        #pragma unroll
        for (int rg = 0; rg < 4; ++rg) {
            s16x4 st;
            st[0] = f2bf(acc[dt][rg * 4 + 0]);
            st[1] = f2bf(acc[dt][rg * 4 + 1]);
            st[2] = f2bf(acc[dt][rg * 4 + 2]);
            st[3] = f2bf(acc[dt][rg * 4 + 3]);
            *(s16x4*)&part[pbase + dt * 32 + rg * 8 + h * 4] = st;
        }
    if (h == 0) {
        size_t mi = ((size_t)split * (BB * NN) + bN + q) * 2;
        ml[mi] = m_use; ml[mi + 1] = l_run;
    }
}

// ---------------------------------------------------------------------------
// Kernel 3: combine KV-split partials -> y [b][n][c] bf16
// ---------------------------------------------------------------------------
template<int SPLIT>
__global__ __launch_bounds__(256) void combine2_kernel(
    const short* __restrict__ part, const float* __restrict__ ml,
    short* __restrict__ y)
{
    int gid = blockIdx.x * 256 + threadIdx.x;     // 16384 * 32
    int qg = gid >> 5;
    int c8 = (gid & 31) << 3;
    float mm[SPLIT], ll[SPLIT];
    float m = -1e30f;
    #pragma unroll
    for (int s = 0; s < SPLIT; ++s) {
        mm[s] = ml[((size_t)s * (BB * NN) + qg) * 2];
        ll[s] = ml[((size_t)s * (BB * NN) + qg) * 2 + 1];
        m = fmaxf(m, mm[s]);
    }
    float den = 0.f, a[SPLIT];
    #pragma unroll
    for (int s = 0; s < SPLIT; ++s) { a[s] = __expf(mm[s] - m); den += a[s] * ll[s]; }
    float o[8];
    #pragma unroll
    for (int j = 0; j < 8; ++j) o[j] = 0.f;
    #pragma unroll
    for (int s = 0; s < SPLIT; ++s) {
        s16x8 p = *(const s16x8*)&part[((size_t)s * (BB * NN) + qg) * CIc + c8];
        #pragma unroll
        for (int j = 0; j < 8; ++j) o[j] += a[s] * bf2f(p[j]);
    }
    float inv = 1.f / den;
    s16x8 st;
    #pragma unroll
    for (int j = 0; j < 8; ++j) st[j] = f2bf(o[j] * inv);
    *(s16x8*)&y[(size_t)qg * CIc + c8] = st;
}

// ---------------------------------------------------------------------------
// Kernel 4: z[b][o][n] = sum_c w_w[o][c]*y[b][n][c] + w_b[o]   (f32 -> d_out)
// ---------------------------------------------------------------------------
__global__ __launch_bounds__(256) void zgemm_kernel(
    const short* __restrict__ y, const short* __restrict__ Wf,
    const float* __restrict__ wb, float* __restrict__ z)
{
    __shared__ char yls[64 * 512];
    const int blk = blockIdx.x;
    const int b   = blk >> 7;
    const int n0  = (blk & 127) << 6;
    const int tid = threadIdx.x;
    #pragma unroll
    for (int ic = 0; ic < 8; ++ic) {
        int chunk = ic * 256 + tid;
        int row = chunk >> 5, c16 = chunk & 31;
        i32x4 v = *(const i32x4*)&y[((size_t)b * NN + n0 + row) * CIc + c16 * 8];
        int addr = row * 512 + ((c16 * 16) ^ ((row & 31) << 4));
        *(i32x4*)(yls + addr) = v;
    }
    __syncthreads();
    const int lane = tid & 63, w = tid >> 6, lo = lane & 15, g = lane >> 4;
    s16x8 afr[8];
    #pragma unroll
    for (int k = 0; k < 8; ++k) {
        int row = w * 16 + lo;
        int addr = row * 512 + ((k * 64 + g * 16) ^ ((row & 31) << 4));
        afr[k] = *(const s16x8*)(yls + addr);
    }
    for (int ot = 0; ot < 16; ++ot) {
        f32x4 acc = {0.f, 0.f, 0.f, 0.f};
        #pragma unroll
        for (int k = 0; k < 8; ++k) {
            s16x8 bfr = *(const s16x8*)&Wf[(size_t)((3 * 16 + ot) * 8 + k) * 512 + lane * 8];
            acc = __builtin_amdgcn_mfma_f32_16x16x32_bf16(afr[k], bfr, acc, 0, 0, 0);
        }
        float bias = wb[ot * 16 + lo];
        float4 st = {acc[0] + bias, acc[1] + bias, acc[2] + bias, acc[3] + bias};
        *(float4*)&z[((size_t)b * CIc + ot * 16 + lo) * NN + n0 + w * 16 + g * 4] = st;
    }
}

// ---------------------------------------------------------------------------
// Kernel 5: per-channel batch stats (mean, rsqrt(var+eps)); 1 block/channel
// ---------------------------------------------------------------------------
__global__ __launch_bounds__(256) void bnstats_kernel(
    const float* __restrict__ z, float* __restrict__ stats)
{
    const int o = blockIdx.x;
    const int tid = threadIdx.x;
    float s = 0.f, s2 = 0.f;
    for (int b = 0; b < BB; ++b) {
        const float* row = &z[((size_t)b * CIc + o) * NN];
        for (int i = tid * 4; i < NN; i += 1024) {
            float4 v = *(const float4*)&row[i];
            s  += v.x + v.y + v.z + v.w;
            s2 += v.x * v.x + v.y * v.y + v.z * v.z + v.w * v.w;
        }
    }
    #pragma unroll
    for (int off = 1; off < 64; off <<= 1) {
        s  += __shfl_xor(s, off);
        s2 += __shfl_xor(s2, off);
    }
    __shared__ float rs[8];
    if ((tid & 63) == 0) { rs[tid >> 6] = s; rs[4 + (tid >> 6)] = s2; }
    __syncthreads();
    if (tid == 0) {
        float S  = rs[0] + rs[1] + rs[2] + rs[3];
        float S2 = rs[4] + rs[5] + rs[6] + rs[7];
        float mean = S / (float)(BB * NN);
        float var  = S2 / (float)(BB * NN) - mean * mean;
        stats[o * 2]     = mean;
        stats[o * 2 + 1] = rsqrtf(var + 1e-5f);
    }
}

// ---------------------------------------------------------------------------
// Kernel 6: in-place BN apply on d_out
// ---------------------------------------------------------------------------
__global__ __launch_bounds__(256) void bnapply_kernel(
    float* __restrict__ z, const float* __restrict__ stats,
    const float* __restrict__ gamma, const float* __restrict__ beta)
{
    int gid = blockIdx.x * 256 + threadIdx.x;
    int idx4 = gid * 4;
    int o = (idx4 >> 13) & 255;
    float mean = stats[o * 2], rs = stats[o * 2 + 1];
    float ga = gamma[o], be = beta[o];
    float4 v = *(const float4*)&z[idx4];
    v.x = (v.x - mean) * rs * ga + be;
    v.y = (v.y - mean) * rs * ga + be;
    v.z = (v.z - mean) * rs * ga + be;
    v.w = (v.w - mean) * rs * ga + be;
    *(float4*)&z[idx4] = v;
}

// ---------------------------------------------------------------------------
extern "C" void kernel_launch(void* const* d_in, const int* in_sizes, int n_in,
                              void* d_out, int out_size, void* d_ws, size_t ws_size,
                              hipStream_t stream) {
    const float* x    = (const float*)d_in[0];
    const float* g_w  = (const float*)d_in[1];
    const float* g_b  = (const float*)d_in[2];
    const float* th_w = (const float*)d_in[3];
    const float* th_b = (const float*)d_in[4];
    const float* ph_w = (const float*)d_in[5];
    const float* ph_b = (const float*)d_in[6];
    const float* w_w  = (const float*)d_in[7];
    const float* w_b  = (const float*)d_in[8];
    const float* bn_g = (const float*)d_in[9];
    const float* bn_b = (const float*)d_in[10];

    char* ws = (char*)d_ws;
    short* Qb    = (short*)ws;                         // 8 MiB (reused as y)
    short* Kf    = (short*)(ws + 8  * 1048576);        // 8 MiB
    short* Vf    = (short*)(ws + 16 * 1048576);        // 8 MiB
    float* ml    = (float*)(ws + 24 * 1048576);        // <= 512 KiB
    float* stats = (float*)(ws + 24 * 1048576 + 524288);
    short* Wfb   = (short*)(ws + 25 * 1048576);        // 512 KiB
    float* z     = (float*)d_out;

    const size_t need4 = (size_t)26 * 1048576 + (size_t)4 * BB * NN * CIc * 2;
    const bool  big    = ws_size >= need4;

    pack_kernel<<<128, 256, 0, stream>>>(th_w, ph_w, g_w, w_w, Wfb);
    proj_kernel<<<768, 256, 0, stream>>>(x, Wfb, th_b, ph_b, g_b, Qb, Kf, Vf);

    if (big) {
        short* part = (short*)(ws + 26 * 1048576);     // 32 MiB
        attn2_kernel<4><<<512, 256, 0, stream>>>(Qb, Kf, Vf, part, ml);
        combine2_kernel<4><<<2048, 256, 0, stream>>>(part, ml, Qb);
    } else {
        short* part = (short*)d_out;                   // 2 splits fit d_out exactly
        attn2_kernel<2><<<256, 256, 0, stream>>>(Qb, Kf, Vf, part, ml);
        combine2_kernel<2><<<2048, 256, 0, stream>>>(part, ml, Qb);
    }

    zgemm_kernel<<<256, 256, 0, stream>>>(Qb, Wfb, w_b, z);
    bnstats_kernel<<<256, 256, 0, stream>>>(z, stats);
    bnapply_kernel<<<4096, 256, 0, stream>>>(z, stats, bn_g, bn_b);
}

// Round 5
// 222.500 us; speedup vs baseline: 7.2306x; 1.4134x over previous
//
#include <hip/hip_runtime.h>
#include <hip/hip_bf16.h>
#include <stdint.h>

// Problem constants
#define BB  2
#define CC  256
#define NN  8192
#define CIc 256

typedef __attribute__((ext_vector_type(4)))  float f32x4;
typedef __attribute__((ext_vector_type(16))) float f32x16;
typedef __attribute__((ext_vector_type(8)))  short s16x8;   // 8 bf16 = 4 VGPR
typedef __attribute__((ext_vector_type(4)))  short s16x4;
typedef __attribute__((ext_vector_type(4)))  int   i32x4;

static __device__ __forceinline__ short f2bf(float f) {
    union { float f; unsigned u; } v; v.f = f;
    unsigned r = (v.u + 0x7FFFu + ((v.u >> 16) & 1u)) >> 16;   // RNE
    return (short)r;
}
static __device__ __forceinline__ float bf2f(short h) {
    union { unsigned u; float f; } v; v.u = ((unsigned)(unsigned short)h) << 16;
    return v.f;
}

// async global->LDS, 16B per lane, dest = lds_base + lane*16 (wave-uniform base)
static __device__ __forceinline__ void gload16(const void* g, void* l) {
    __builtin_amdgcn_global_load_lds(
        (const __attribute__((address_space(1))) unsigned int*)g,
        (__attribute__((address_space(3))) unsigned int*)l, 16, 0, 0);
}

// ---------------------------------------------------------------------------
// Kernel 0: pack the 4 weight matrices (theta, phi, g, w) f32[256][256] into
// bf16 MFMA-fragment order:  Wf[m][ot][ks][lane][8e] =
//   W[ot*16 + (lane&15)][ks*32 + (lane>>4)*8 + e]
// ---------------------------------------------------------------------------
__global__ __launch_bounds__(256) void pack_kernel(
    const float* __restrict__ tw, const float* __restrict__ pw,
    const float* __restrict__ gw, const float* __restrict__ ww,
    short* __restrict__ Wf)
{
    int gid  = blockIdx.x * 256 + threadIdx.x;   // 32768 threads
    int lane = gid & 63;
    int grp  = gid >> 6;                          // [0,512): m*128 + ot*8 + ks
    int ks = grp & 7, ot = (grp >> 3) & 15, m = grp >> 7;
    const float* W = (m == 0) ? tw : (m == 1) ? pw : (m == 2) ? gw : ww;
    const float* p = &W[(size_t)(ot * 16 + (lane & 15)) * 256 + ks * 32 + (lane >> 4) * 8];
    float4 a = *(const float4*)p, c = *(const float4*)(p + 4);
    s16x8 o;
    o[0] = f2bf(a.x); o[1] = f2bf(a.y); o[2] = f2bf(a.z); o[3] = f2bf(a.w);
    o[4] = f2bf(c.x); o[5] = f2bf(c.y); o[6] = f2bf(c.z); o[7] = f2bf(c.w);
    *(s16x8*)&Wf[(size_t)gid * 8] = o;
}

// ---------------------------------------------------------------------------
// Kernel 1: projections.  grid = 3 (matrix) x B x N/64.  One matrix per block.
//   m=0 theta -> Qb [b][n][c] row-major bf16
//   m=1 phi   -> Kf fragment-packed: Kf[b][t][ks(16)][L(64)][8]
//   m=2 g     -> Vf fragment-packed: Vf[b][t][i(16)][L(64)][8]
// ---------------------------------------------------------------------------
__global__ __launch_bounds__(256) void proj_kernel(
    const float* __restrict__ x, const short* __restrict__ Wf,
    const float* __restrict__ tb, const float* __restrict__ pb,
    const float* __restrict__ gb,
    short* __restrict__ Qb, short* __restrict__ Kf, short* __restrict__ Vf)
{
    __shared__ char xls[64 * 512];   // xT tile [n(64)][c(256)] bf16, XOR-swizzled
    const int blk = blockIdx.x;            // 768 blocks
    const int m   = blk % 3;
    const int r2  = blk / 3;
    const int b   = r2 >> 7;
    const int n0  = (r2 & 127) << 6;
    const int tid = threadIdx.x;

    for (int it = 0; it < 16; ++it) {
        int chunk = it * 256 + tid;
        int c  = chunk >> 4;
        int n4 = (chunk & 15) << 2;
        const float4 v = *(const float4*)&x[((size_t)b * CC + c) * NN + n0 + n4];
        float vv[4] = {v.x, v.y, v.z, v.w};
        #pragma unroll
        for (int j = 0; j < 4; ++j) {
            int row = n4 + j;
            int addr = row * 512 + ((c * 2) ^ ((row & 31) << 4));
            *(short*)(xls + addr) = f2bf(vv[j]);
        }
    }
    __syncthreads();

    const int lane = tid & 63, w = tid >> 6;
    const int lo = lane & 15, g = lane >> 4;

    s16x8 bfr[8];
    #pragma unroll
    for (int k = 0; k < 8; ++k) {
        int row = w * 16 + lo;
        int addr = row * 512 + ((k * 64 + g * 16) ^ ((row & 31) << 4));
        bfr[k] = *(const s16x8*)(xls + addr);
    }

    const float* bias = (m == 0) ? tb : (m == 1) ? pb : gb;
    const size_t wfm = (size_t)m * 16 * 8 * 512;

    for (int ot = 0; ot < 16; ++ot) {
        s16x8 afr[8];
        #pragma unroll
        for (int k = 0; k < 8; ++k)
            afr[k] = *(const s16x8*)&Wf[wfm + (size_t)(ot * 8 + k) * 512 + lane * 8];
        f32x4 acc = {0.f, 0.f, 0.f, 0.f};
        if (m < 2) {
            #pragma unroll
            for (int k = 0; k < 8; ++k)
                acc = __builtin_amdgcn_mfma_f32_16x16x32_bf16(afr[k], bfr[k], acc, 0, 0, 0);
        } else {
            #pragma unroll
            for (int k = 0; k < 8; ++k)
                acc = __builtin_amdgcn_mfma_f32_16x16x32_bf16(bfr[k], afr[k], acc, 0, 0, 0);
        }

        if (m == 0) {
            const float4 bi = *(const float4*)&bias[ot * 16 + g * 4];
            int n = n0 + w * 16 + lo;
            s16x4 st;
            st[0] = f2bf(acc[0] + bi.x);
            st[1] = f2bf(acc[1] + bi.y);
            st[2] = f2bf(acc[2] + bi.z);
            st[3] = f2bf(acc[3] + bi.w);
            *(s16x4*)&Qb[((size_t)b * NN + n) * CIc + ot * 16 + g * 4] = st;
        } else if (m == 1) {
            const float4 bi = *(const float4*)&bias[ot * 16 + g * 4];
            int n = n0 + w * 16 + lo;
            s16x4 st;
            st[0] = f2bf(acc[0] + bi.x);
            st[1] = f2bf(acc[1] + bi.y);
            st[2] = f2bf(acc[2] + bi.z);
            st[3] = f2bf(acc[3] + bi.w);
            size_t a = ((((size_t)b * 256 + (n >> 5)) * 16 + ot) * 64
                        + (n & 31) + 32 * (g >> 1)) * 8 + (g & 1) * 4;
            *(s16x4*)&Kf[a] = st;
        } else {
            int nb = n0 + w * 16 + g * 4;
            int o  = ot * 16 + lo;
            float bo = bias[o];
            s16x4 st;
            st[0] = f2bf(acc[0] + bo);
            st[1] = f2bf(acc[1] + bo);
            st[2] = f2bf(acc[2] + bo);
            st[3] = f2bf(acc[3] + bo);
            size_t a = ((((size_t)b * 256 + (nb >> 5)) * 16 + (w & 1) * 8 + (ot >> 1)) * 64
                        + (ot & 1) * 16 + lo + 32 * (g >> 1)) * 8 + (g & 1) * 4;
            *(s16x4*)&Vf[a] = st;
        }
    }
}

// ---------------------------------------------------------------------------
// Kernel 2: flash attention, 32x32x16 MFMA, swapped QK^T, KV-split.
//   wave = 32 q rows, block = 4 waves (128 q).  K AND V staged in LDS
//   (double-buffered 2x32KB, fragment-linear, fully-coalesced gload16 from
//   packed Kf/Vf).  part written in lane-linear packed layout:
//   part_p[s][b][qb(256)][slot=dt*4+rg (32)][lane(64)][4e]
// ---------------------------------------------------------------------------
template<int SPLIT>
__global__ __launch_bounds__(256, 2) void attn2_kernel(
    const short* __restrict__ Qb, const short* __restrict__ Kf,
    const short* __restrict__ Vf,
    short* __restrict__ part,    // packed, unnormalized
    float* __restrict__ ml)      // [SPLIT][B*N][2]
{
    __shared__ char lds[65536];  // 2 bufs x (K 16KB | V 16KB)
    const int blk   = blockIdx.x;
    const int combo = blk & (2 * SPLIT - 1);      // XCD-affine grouping
    const int split = combo >> 1;
    const int b     = combo & 1;
    const int qblk  = blk / (2 * SPLIT);          // 0..63
    const int tid = threadIdx.x, lane = tid & 63, w = tid >> 6;
    const int l31 = lane & 31, h = lane >> 5;
    const int q   = qblk * 128 + w * 32 + l31;
    const size_t bN = (size_t)b * NN;
    const int tgbase = (split * (NN / SPLIT)) >> 5;
    const int NT = (NN / SPLIT) / 32;

    // ---- stage tile 0 (K: insts 0-15, V: insts 16-31; each wave issues 8)
    #pragma unroll
    for (int j = 0; j < 8; ++j) {
        const int inst = w * 8 + j;
        if (inst < 16)
            gload16(&Kf[(((size_t)(b * 256 + tgbase) * 16) + inst) * 512 + lane * 8],
                    lds + inst * 1024);
        else
            gload16(&Vf[(((size_t)(b * 256 + tgbase) * 16) + (inst - 16)) * 512 + lane * 8],
                    lds + 16384 + (inst - 16) * 1024);
    }

    // ---- Q fragments: qf[ks] = Q[q][ks*16 + h*8 .. +7]
    s16x8 qf[16];
    #pragma unroll
    for (int ks = 0; ks < 16; ++ks)
        qf[ks] = *(const s16x8*)&Qb[(bN + q) * CIc + ks * 16 + h * 8];

    f32x16 acc[8];
    #pragma unroll
    for (int dt = 0; dt < 8; ++dt)
        #pragma unroll
        for (int r = 0; r < 16; ++r) acc[dt][r] = 0.f;
    float m_use = -1e30f, l_run = 0.f;

    for (int t = 0; t < NT; ++t) {
        __syncthreads();   // tile t staged
        const char* cbuf = lds + (t & 1) * 32768;
        const int tg = tgbase + t;
        if (t + 1 < NT) {
            char* nbuf = lds + ((t + 1) & 1) * 32768;
            #pragma unroll
            for (int j = 0; j < 8; ++j) {
                const int inst = w * 8 + j;
                if (inst < 16)
                    gload16(&Kf[(((size_t)(b * 256 + tg + 1) * 16) + inst) * 512 + lane * 8],
                            nbuf + inst * 1024);
                else
                    gload16(&Vf[(((size_t)(b * 256 + tg + 1) * 16) + (inst - 16)) * 512 + lane * 8],
                            nbuf + 16384 + (inst - 16) * 1024);
            }
        }

        // ---- QK^T: S[kv=32][q=32]; lane: q=l31, kv(reg)=(reg&3)+8*(reg>>2)+4h
        f32x16 sacc;
        #pragma unroll
        for (int r = 0; r < 16; ++r) sacc[r] = 0.f;
        __builtin_amdgcn_s_setprio(1);
        #pragma unroll
        for (int ks = 0; ks < 16; ++ks) {
            s16x8 kf = *(const s16x8*)(cbuf + ks * 1024 + lane * 16);
            sacc = __builtin_amdgcn_mfma_f32_32x32x16_bf16(kf, qf[ks], sacc, 0, 0, 0);
        }
        __builtin_amdgcn_s_setprio(0);

        // ---- online softmax (lane-local; partner lane^32 has same q)
        float tmax = fmaxf(sacc[0], sacc[1]);
        #pragma unroll
        for (int r = 2; r < 16; ++r) tmax = fmaxf(tmax, sacc[r]);
        tmax = fmaxf(tmax, __shfl_xor(tmax, 32));
        if (!__all(tmax - m_use <= 8.0f)) {       // defer-max THR=8
            float mnew = fmaxf(m_use, tmax);
            float sc = __expf(m_use - mnew);
            l_run *= sc;
            #pragma unroll
            for (int dt = 0; dt < 8; ++dt)
                #pragma unroll
                for (int r = 0; r < 16; ++r) acc[dt][r] *= sc;
            m_use = mnew;
        }
        float sum = 0.f;
        #pragma unroll
        for (int r = 0; r < 16; ++r) {
            float p = __expf(sacc[r] - m_use);
            sacc[r] = p; sum += p;
        }
        sum += __shfl_xor(sum, 32);
        l_run += sum;

        // ---- P -> bf16 B-frags, slot k = h*8+e (shfl_xor cross-half)
        union { int wd[4]; s16x8 v; } f0, f1;
        {
            int w01, w23, w45, w67;
            asm("v_cvt_pk_bf16_f32 %0, %1, %2" : "=v"(w01) : "v"(sacc[0]), "v"(sacc[1]));
            asm("v_cvt_pk_bf16_f32 %0, %1, %2" : "=v"(w23) : "v"(sacc[2]), "v"(sacc[3]));
            asm("v_cvt_pk_bf16_f32 %0, %1, %2" : "=v"(w45) : "v"(sacc[4]), "v"(sacc[5]));
            asm("v_cvt_pk_bf16_f32 %0, %1, %2" : "=v"(w67) : "v"(sacc[6]), "v"(sacc[7]));
            int x01 = __shfl_xor(w01, 32), x23 = __shfl_xor(w23, 32);
            int x45 = __shfl_xor(w45, 32), x67 = __shfl_xor(w67, 32);
            f0.wd[0] = h ? x45 : w01;
            f0.wd[1] = h ? x67 : w23;
            f0.wd[2] = h ? w45 : x01;
            f0.wd[3] = h ? w67 : x23;
        }
        {
            int w01, w23, w45, w67;
            asm("v_cvt_pk_bf16_f32 %0, %1, %2" : "=v"(w01) : "v"(sacc[8]),  "v"(sacc[9]));
            asm("v_cvt_pk_bf16_f32 %0, %1, %2" : "=v"(w23) : "v"(sacc[10]), "v"(sacc[11]));
            asm("v_cvt_pk_bf16_f32 %0, %1, %2" : "=v"(w45) : "v"(sacc[12]), "v"(sacc[13]));
            asm("v_cvt_pk_bf16_f32 %0, %1, %2" : "=v"(w67) : "v"(sacc[14]), "v"(sacc[15]));
            int x01 = __shfl_xor(w01, 32), x23 = __shfl_xor(w23, 32);
            int x45 = __shfl_xor(w45, 32), x67 = __shfl_xor(w67, 32);
            f1.wd[0] = h ? x45 : w01;
            f1.wd[1] = h ? x67 : w23;
            f1.wd[2] = h ? w45 : x01;
            f1.wd[3] = h ? w67 : x23;
        }

        // ---- PV: O^T[d][q] += V^T-frag x P-frag (V from LDS)
        const char* vbuf = cbuf + 16384;
        __builtin_amdgcn_s_setprio(1);
        #pragma unroll
        for (int dt = 0; dt < 8; ++dt) {
            s16x8 v0 = *(const s16x8*)(vbuf + (dt) * 1024 + lane * 16);
            s16x8 v1 = *(const s16x8*)(vbuf + (8 + dt) * 1024 + lane * 16);
            acc[dt] = __builtin_amdgcn_mfma_f32_32x32x16_bf16(v0, f0.v, acc[dt], 0, 0, 0);
            acc[dt] = __builtin_amdgcn_mfma_f32_32x32x16_bf16(v1, f1.v, acc[dt], 0, 0, 0);
        }
        __builtin_amdgcn_s_setprio(0);
    }

    // ---- epilogue: packed unnormalized partial + (m,l)
    // part_p[s][b][qb][slot=dt*4+rg][lane][4e]; e=j <-> d = dt*32+rg*8+4h+j
    const int qb = qblk * 4 + w;
    const size_t pb2 = (((size_t)(split * 2 + b) * 256 + qb) * 32) * 256;  // *64 lanes *4e
    #pragma unroll
    for (int dt = 0; dt < 8; ++dt)
        #pragma unroll
        for (int rg = 0; rg < 4; ++rg) {
            s16x4 st;
            st[0] = f2bf(acc[dt][rg * 4 + 0]);
            st[1] = f2bf(acc[dt][rg * 4 + 1]);
            st[2] = f2bf(acc[dt][rg * 4 + 2]);
            st[3] = f2bf(acc[dt][rg * 4 + 3]);
            *(s16x4*)&part[pb2 + (size_t)(dt * 4 + rg) * 256 + lane * 4] = st;
        }
    if (h == 0) {
        size_t mi = ((size_t)split * (BB * NN) + bN + q) * 2;
        ml[mi] = m_use; ml[mi + 1] = l_run;
    }
}

// ---------------------------------------------------------------------------
// Kernel 3: combine packed KV-split partials -> yp (zgemm A-frag layout)
//   yp[b][nt(512)][k(8)][lane(64)][8e] = y[nt*16+(lane&15)][k*32+(lane>>4)*8+e]
// ---------------------------------------------------------------------------
template<int SPLIT>
__global__ __launch_bounds__(256) void combine2_kernel(
    const short* __restrict__ part, const float* __restrict__ ml,
    short* __restrict__ yp)
{
    int gid  = blockIdx.x * 256 + threadIdx.x;   // 1,048,576 threads
    int lane = gid & 63;
    int slot = (gid >> 6) & 31;
    int qb   = (gid >> 11) & 255;
    int b    = gid >> 19;
    int dt = slot >> 2, rg = slot & 3;
    int l31 = lane & 31, h = lane >> 5;
    int q = qb * 32 + l31;

    float mm[SPLIT], ll[SPLIT];
    float m = -1e30f;
    #pragma unroll
    for (int s = 0; s < SPLIT; ++s) {
        mm[s] = ml[((size_t)s * (BB * NN) + (size_t)b * NN + q) * 2];
        ll[s] = ml[((size_t)s * (BB * NN) + (size_t)b * NN + q) * 2 + 1];
        m = fmaxf(m, mm[s]);
    }
    float den = 0.f, a[SPLIT];
    #pragma unroll
    for (int s = 0; s < SPLIT; ++s) { a[s] = __expf(mm[s] - m); den += a[s] * ll[s]; }
    float o[4] = {0.f, 0.f, 0.f, 0.f};
    #pragma unroll
    for (int s = 0; s < SPLIT; ++s) {
        s16x4 p = *(const s16x4*)&part[((((size_t)(s * 2 + b) * 256 + qb) * 32 + slot) * 64 + lane) * 4];
        #pragma unroll
        for (int j = 0; j < 4; ++j) o[j] += a[s] * bf2f(p[j]);
    }
    float inv = 1.f / den;
    s16x4 st;
    #pragma unroll
    for (int j = 0; j < 4; ++j) st[j] = f2bf(o[j] * inv);
    // yp coords: nt=q>>4, k=dt, lane'=(q&15)+rg*16, e'=h*4+j
    size_t a2 = ((((size_t)b * 512 + (q >> 4)) * 8 + dt) * 64 + (q & 15) + rg * 16) * 8 + h * 4;
    *(s16x4*)&yp[a2] = st;
}

// ---------------------------------------------------------------------------
// Kernel 4: z[b][o][n] = sum_c w_w[o][c]*y[b][n][c] + w_b[o]   (f32 -> d_out)
// A-frags straight from packed yp (no LDS, no barrier).
// ---------------------------------------------------------------------------
__global__ __launch_bounds__(256) void zgemm_kernel(
    const short* __restrict__ yp, const short* __restrict__ Wf,
    const float* __restrict__ wb, float* __restrict__ z)
{
    const int blk = blockIdx.x;
    const int b   = blk >> 7;
    const int n0  = (blk & 127) << 6;
    const int tid = threadIdx.x;
    const int lane = tid & 63, w = tid >> 6, lo = lane & 15, g = lane >> 4;

    s16x8 afr[8];
    #pragma unroll
    for (int k = 0; k < 8; ++k)
        afr[k] = *(const s16x8*)&yp[((((size_t)b * 512 + (n0 >> 4) + w) * 8 + k) * 64 + lane) * 8];

    for (int ot = 0; ot < 16; ++ot) {
        f32x4 acc = {0.f, 0.f, 0.f, 0.f};
        #pragma unroll
        for (int k = 0; k < 8; ++k) {
            s16x8 bfr = *(const s16x8*)&Wf[(size_t)((3 * 16 + ot) * 8 + k) * 512 + lane * 8];
            acc = __builtin_amdgcn_mfma_f32_16x16x32_bf16(afr[k], bfr, acc, 0, 0, 0);
        }
        float bias = wb[ot * 16 + lo];
        float4 st = {acc[0] + bias, acc[1] + bias, acc[2] + bias, acc[3] + bias};
        *(float4*)&z[((size_t)b * CIc + ot * 16 + lo) * NN + n0 + w * 16 + g * 4] = st;
    }
}

// ---------------------------------------------------------------------------
// Kernel 5: per-channel batch stats (mean, rsqrt(var+eps)); 1 block/channel
// ---------------------------------------------------------------------------
__global__ __launch_bounds__(256) void bnstats_kernel(
    const float* __restrict__ z, float* __restrict__ stats)
{
    const int o = blockIdx.x;
    const int tid = threadIdx.x;
    float s = 0.f, s2 = 0.f;
    for (int b = 0; b < BB; ++b) {
        const float* row = &z[((size_t)b * CIc + o) * NN];
        for (int i = tid * 4; i < NN; i += 1024) {
            float4 v = *(const float4*)&row[i];
            s  += v.x + v.y + v.z + v.w;
            s2 += v.x * v.x + v.y * v.y + v.z * v.z + v.w * v.w;
        }
    }
    #pragma unroll
    for (int off = 1; off < 64; off <<= 1) {
        s  += __shfl_xor(s, off);
        s2 += __shfl_xor(s2, off);
    }
    __shared__ float rs[8];
    if ((tid & 63) == 0) { rs[tid >> 6] = s; rs[4 + (tid >> 6)] = s2; }
    __syncthreads();
    if (tid == 0) {
        float S  = rs[0] + rs[1] + rs[2] + rs[3];
        float S2 = rs[4] + rs[5] + rs[6] + rs[7];
        float mean = S / (float)(BB * NN);
        float var  = S2 / (float)(BB * NN) - mean * mean;
        stats[o * 2]     = mean;
        stats[o * 2 + 1] = rsqrtf(var + 1e-5f);
    }
}

// ---------------------------------------------------------------------------
// Kernel 6: in-place BN apply on d_out
// ---------------------------------------------------------------------------
__global__ __launch_bounds__(256) void bnapply_kernel(
    float* __restrict__ z, const float* __restrict__ stats,
    const float* __restrict__ gamma, const float* __restrict__ beta)
{
    int gid = blockIdx.x * 256 + threadIdx.x;
    int idx4 = gid * 4;
    int o = (idx4 >> 13) & 255;
    float mean = stats[o * 2], rs = stats[o * 2 + 1];
    float ga = gamma[o], be = beta[o];
    float4 v = *(const float4*)&z[idx4];
    v.x = (v.x - mean) * rs * ga + be;
    v.y = (v.y - mean) * rs * ga + be;
    v.z = (v.z - mean) * rs * ga + be;
    v.w = (v.w - mean) * rs * ga + be;
    *(float4*)&z[idx4] = v;
}

// ---------------------------------------------------------------------------
extern "C" void kernel_launch(void* const* d_in, const int* in_sizes, int n_in,
                              void* d_out, int out_size, void* d_ws, size_t ws_size,
                              hipStream_t stream) {
    const float* x    = (const float*)d_in[0];
    const float* g_w  = (const float*)d_in[1];
    const float* g_b  = (const float*)d_in[2];
    const float* th_w = (const float*)d_in[3];
    const float* th_b = (const float*)d_in[4];
    const float* ph_w = (const float*)d_in[5];
    const float* ph_b = (const float*)d_in[6];
    const float* w_w  = (const float*)d_in[7];
    const float* w_b  = (const float*)d_in[8];
    const float* bn_g = (const float*)d_in[9];
    const float* bn_b = (const float*)d_in[10];

    char* ws = (char*)d_ws;
    short* Qb    = (short*)ws;                         // 8 MiB (reused as yp)
    short* Kf    = (short*)(ws + 8  * 1048576);        // 8 MiB
    short* Vf    = (short*)(ws + 16 * 1048576);        // 8 MiB
    float* ml    = (float*)(ws + 24 * 1048576);        // <= 512 KiB
    float* stats = (float*)(ws + 24 * 1048576 + 524288);
    short* Wfb   = (short*)(ws + 25 * 1048576);        // 512 KiB
    float* z     = (float*)d_out;

    const size_t need4 = (size_t)26 * 1048576 + (size_t)4 * BB * NN * CIc * 2;
    const bool  big    = ws_size >= need4;

    pack_kernel<<<128, 256, 0, stream>>>(th_w, ph_w, g_w, w_w, Wfb);
    proj_kernel<<<768, 256, 0, stream>>>(x, Wfb, th_b, ph_b, g_b, Qb, Kf, Vf);

    if (big) {
        short* part = (short*)(ws + 26 * 1048576);     // 32 MiB
        attn2_kernel<4><<<512, 256, 0, stream>>>(Qb, Kf, Vf, part, ml);
        combine2_kernel<4><<<4096, 256, 0, stream>>>(part, ml, Qb);
    } else {
        short* part = (short*)d_out;                   // 2 splits fit d_out exactly
        attn2_kernel<2><<<256, 256, 0, stream>>>(Qb, Kf, Vf, part, ml);
        combine2_kernel<2><<<4096, 256, 0, stream>>>(part, ml, Qb);
    }

    zgemm_kernel<<<256, 256, 0, stream>>>(Qb, Wfb, w_b, z);
    bnstats_kernel<<<256, 256, 0, stream>>>(z, stats);
    bnapply_kernel<<<4096, 256, 0, stream>>>(z, stats, bn_g, bn_b);
}

// Round 6
// 213.643 us; speedup vs baseline: 7.5303x; 1.0415x over previous
//
#include <hip/hip_runtime.h>
#include <hip/hip_bf16.h>
#include <stdint.h>

// Problem constants
#define BB  2
#define CC  256
#define NN  8192
#define CIc 256

typedef __attribute__((ext_vector_type(4)))  float f32x4;
typedef __attribute__((ext_vector_type(16))) float f32x16;
typedef __attribute__((ext_vector_type(8)))  short s16x8;   // 8 bf16 = 4 VGPR
typedef __attribute__((ext_vector_type(4)))  short s16x4;
typedef __attribute__((ext_vector_type(4)))  int   i32x4;
typedef __attribute__((ext_vector_type(2)))  int   i32x2;

static __device__ __forceinline__ short f2bf(float f) {
    union { float f; unsigned u; } v; v.f = f;
    unsigned r = (v.u + 0x7FFFu + ((v.u >> 16) & 1u)) >> 16;   // RNE
    return (short)r;
}
static __device__ __forceinline__ float bf2f(short h) {
    union { unsigned u; float f; } v; v.u = ((unsigned)(unsigned short)h) << 16;
    return v.f;
}

// async global->LDS, 16B per lane, dest = lds_base + lane*16 (wave-uniform base)
static __device__ __forceinline__ void gload16(const void* g, void* l) {
    __builtin_amdgcn_global_load_lds(
        (const __attribute__((address_space(1))) unsigned int*)g,
        (__attribute__((address_space(3))) unsigned int*)l, 16, 0, 0);
}

// ---------------------------------------------------------------------------
// Kernel 0: pack the 4 weight matrices (theta, phi, g, w) f32[256][256] into
// bf16 MFMA-fragment order:  Wf[m][ot][ks][lane][8e] =
//   W[ot*16 + (lane&15)][ks*32 + (lane>>4)*8 + e]
// ---------------------------------------------------------------------------
__global__ __launch_bounds__(256) void pack_kernel(
    const float* __restrict__ tw, const float* __restrict__ pw,
    const float* __restrict__ gw, const float* __restrict__ ww,
    short* __restrict__ Wf)
{
    int gid  = blockIdx.x * 256 + threadIdx.x;   // 32768 threads
    int lane = gid & 63;
    int grp  = gid >> 6;                          // [0,512): m*128 + ot*8 + ks
    int ks = grp & 7, ot = (grp >> 3) & 15, m = grp >> 7;
    const float* W = (m == 0) ? tw : (m == 1) ? pw : (m == 2) ? gw : ww;
    const float* p = &W[(size_t)(ot * 16 + (lane & 15)) * 256 + ks * 32 + (lane >> 4) * 8];
    float4 a = *(const float4*)p, c = *(const float4*)(p + 4);
    s16x8 o;
    o[0] = f2bf(a.x); o[1] = f2bf(a.y); o[2] = f2bf(a.z); o[3] = f2bf(a.w);
    o[4] = f2bf(c.x); o[5] = f2bf(c.y); o[6] = f2bf(c.z); o[7] = f2bf(c.w);
    *(s16x8*)&Wf[(size_t)gid * 8] = o;
}

// ---------------------------------------------------------------------------
// Kernel 1: projections.  grid = 3 (matrix) x B x N/64.  One matrix per block.
//   m=0 theta -> Qb [b][n][c] row-major bf16
//   m=1 phi   -> Kf fragment-packed: Kf[b][t][ks(16)][L(64)][8]
//   m=2 g     -> Vf fragment-packed: Vf[b][t][i(16)][L(64)][8]
// ---------------------------------------------------------------------------
__global__ __launch_bounds__(256) void proj_kernel(
    const float* __restrict__ x, const short* __restrict__ Wf,
    const float* __restrict__ tb, const float* __restrict__ pb,
    const float* __restrict__ gb,
    short* __restrict__ Qb, short* __restrict__ Kf, short* __restrict__ Vf)
{
    __shared__ char xls[64 * 512];   // xT tile [n(64)][c(256)] bf16, XOR-swizzled
    const int blk = blockIdx.x;            // 768 blocks
    const int m   = blk % 3;
    const int r2  = blk / 3;
    const int b   = r2 >> 7;
    const int n0  = (r2 & 127) << 6;
    const int tid = threadIdx.x;

    for (int it = 0; it < 16; ++it) {
        int chunk = it * 256 + tid;
        int c  = chunk >> 4;
        int n4 = (chunk & 15) << 2;
        const float4 v = *(const float4*)&x[((size_t)b * CC + c) * NN + n0 + n4];
        float vv[4] = {v.x, v.y, v.z, v.w};
        #pragma unroll
        for (int j = 0; j < 4; ++j) {
            int row = n4 + j;
            int addr = row * 512 + ((c * 2) ^ ((row & 31) << 4));
            *(short*)(xls + addr) = f2bf(vv[j]);
        }
    }
    __syncthreads();

    const int lane = tid & 63, w = tid >> 6;
    const int lo = lane & 15, g = lane >> 4;

    s16x8 bfr[8];
    #pragma unroll
    for (int k = 0; k < 8; ++k) {
        int row = w * 16 + lo;
        int addr = row * 512 + ((k * 64 + g * 16) ^ ((row & 31) << 4));
        bfr[k] = *(const s16x8*)(xls + addr);
    }

    const float* bias = (m == 0) ? tb : (m == 1) ? pb : gb;
    const size_t wfm = (size_t)m * 16 * 8 * 512;

    for (int ot = 0; ot < 16; ++ot) {
        s16x8 afr[8];
        #pragma unroll
        for (int k = 0; k < 8; ++k)
            afr[k] = *(const s16x8*)&Wf[wfm + (size_t)(ot * 8 + k) * 512 + lane * 8];
        f32x4 acc = {0.f, 0.f, 0.f, 0.f};
        if (m < 2) {
            #pragma unroll
            for (int k = 0; k < 8; ++k)
                acc = __builtin_amdgcn_mfma_f32_16x16x32_bf16(afr[k], bfr[k], acc, 0, 0, 0);
        } else {
            #pragma unroll
            for (int k = 0; k < 8; ++k)
                acc = __builtin_amdgcn_mfma_f32_16x16x32_bf16(bfr[k], afr[k], acc, 0, 0, 0);
        }

        if (m == 0) {
            const float4 bi = *(const float4*)&bias[ot * 16 + g * 4];
            int n = n0 + w * 16 + lo;
            s16x4 st;
            st[0] = f2bf(acc[0] + bi.x);
            st[1] = f2bf(acc[1] + bi.y);
            st[2] = f2bf(acc[2] + bi.z);
            st[3] = f2bf(acc[3] + bi.w);
            *(s16x4*)&Qb[((size_t)b * NN + n) * CIc + ot * 16 + g * 4] = st;
        } else if (m == 1) {
            const float4 bi = *(const float4*)&bias[ot * 16 + g * 4];
            int n = n0 + w * 16 + lo;
            s16x4 st;
            st[0] = f2bf(acc[0] + bi.x);
            st[1] = f2bf(acc[1] + bi.y);
            st[2] = f2bf(acc[2] + bi.z);
            st[3] = f2bf(acc[3] + bi.w);
            size_t a = ((((size_t)b * 256 + (n >> 5)) * 16 + ot) * 64
                        + (n & 31) + 32 * (g >> 1)) * 8 + (g & 1) * 4;
            *(s16x4*)&Kf[a] = st;
        } else {
            int nb = n0 + w * 16 + g * 4;
            int o  = ot * 16 + lo;
            float bo = bias[o];
            s16x4 st;
            st[0] = f2bf(acc[0] + bo);
            st[1] = f2bf(acc[1] + bo);
            st[2] = f2bf(acc[2] + bo);
            st[3] = f2bf(acc[3] + bo);
            size_t a = ((((size_t)b * 256 + (nb >> 5)) * 16 + (w & 1) * 8 + (ot >> 1)) * 64
                        + (ot & 1) * 16 + lo + 32 * (g >> 1)) * 8 + (g & 1) * 4;
            *(s16x4*)&Vf[a] = st;
        }
    }
}

// ---------------------------------------------------------------------------
// Kernel 2: flash attention, 32x32x16 MFMA, swapped QK^T, KV-split.
//   wave = 32 q rows, block = 4 waves (128 q).  K AND V staged in LDS
//   (double-buffered 2x32KB, fragment-linear, coalesced gload16 from packed
//   Kf/Vf).  P-pack cross-half exchange via permlane32_swap (VALU crossbar,
//   no LDS round-trip).  part written lane-linear packed:
//   part_p[s][b][qb(256)][slot=dt*4+rg (32)][lane(64)][4e]
// ---------------------------------------------------------------------------
template<int SPLIT>
__global__ __launch_bounds__(256, 2) void attn2_kernel(
    const short* __restrict__ Qb, const short* __restrict__ Kf,
    const short* __restrict__ Vf,
    short* __restrict__ part,    // packed, unnormalized
    float* __restrict__ ml)      // [SPLIT][B*N][2]
{
    __shared__ char lds[65536];  // 2 bufs x (K 16KB | V 16KB)
    const int blk   = blockIdx.x;
    const int combo = blk & (2 * SPLIT - 1);      // XCD-affine grouping
    const int split = combo >> 1;
    const int b     = combo & 1;
    const int qblk  = blk / (2 * SPLIT);          // 0..63
    const int tid = threadIdx.x, lane = tid & 63, w = tid >> 6;
    const int l31 = lane & 31, h = lane >> 5;
    const int q   = qblk * 128 + w * 32 + l31;
    const size_t bN = (size_t)b * NN;
    const int tgbase = (split * (NN / SPLIT)) >> 5;
    const int NT = (NN / SPLIT) / 32;

    // ---- stage tile 0 (K: insts 0-15, V: insts 16-31; each wave issues 8)
    #pragma unroll
    for (int j = 0; j < 8; ++j) {
        const int inst = w * 8 + j;
        if (inst < 16)
            gload16(&Kf[(((size_t)(b * 256 + tgbase) * 16) + inst) * 512 + lane * 8],
                    lds + inst * 1024);
        else
            gload16(&Vf[(((size_t)(b * 256 + tgbase) * 16) + (inst - 16)) * 512 + lane * 8],
                    lds + 16384 + (inst - 16) * 1024);
    }

    // ---- Q fragments: qf[ks] = Q[q][ks*16 + h*8 .. +7]
    s16x8 qf[16];
    #pragma unroll
    for (int ks = 0; ks < 16; ++ks)
        qf[ks] = *(const s16x8*)&Qb[(bN + q) * CIc + ks * 16 + h * 8];

    f32x16 acc[8];
    #pragma unroll
    for (int dt = 0; dt < 8; ++dt)
        #pragma unroll
        for (int r = 0; r < 16; ++r) acc[dt][r] = 0.f;
    float m_use = -1e30f, l_run = 0.f;

    for (int t = 0; t < NT; ++t) {
        __syncthreads();   // tile t staged
        const char* cbuf = lds + (t & 1) * 32768;
        const int tg = tgbase + t;
        if (t + 1 < NT) {
            char* nbuf = lds + ((t + 1) & 1) * 32768;
            #pragma unroll
            for (int j = 0; j < 8; ++j) {
                const int inst = w * 8 + j;
                if (inst < 16)
                    gload16(&Kf[(((size_t)(b * 256 + tg + 1) * 16) + inst) * 512 + lane * 8],
                            nbuf + inst * 1024);
                else
                    gload16(&Vf[(((size_t)(b * 256 + tg + 1) * 16) + (inst - 16)) * 512 + lane * 8],
                            nbuf + 16384 + (inst - 16) * 1024);
            }
        }

        // ---- QK^T: S[kv=32][q=32]; lane: q=l31, kv(reg)=(reg&3)+8*(reg>>2)+4h
        f32x16 sacc;
        #pragma unroll
        for (int r = 0; r < 16; ++r) sacc[r] = 0.f;
        __builtin_amdgcn_s_setprio(1);
        #pragma unroll
        for (int ks = 0; ks < 16; ++ks) {
            s16x8 kf = *(const s16x8*)(cbuf + ks * 1024 + lane * 16);
            sacc = __builtin_amdgcn_mfma_f32_32x32x16_bf16(kf, qf[ks], sacc, 0, 0, 0);
        }
        __builtin_amdgcn_s_setprio(0);

        // ---- online softmax (lane-local; partner lane^32 has same q)
        float tmax = fmaxf(sacc[0], sacc[1]);
        #pragma unroll
        for (int r = 2; r < 16; ++r) tmax = fmaxf(tmax, sacc[r]);
        tmax = fmaxf(tmax, __shfl_xor(tmax, 32));
        if (!__all(tmax - m_use <= 8.0f)) {       // defer-max THR=8
            float mnew = fmaxf(m_use, tmax);
            float sc = __expf(m_use - mnew);
            l_run *= sc;
            #pragma unroll
            for (int dt = 0; dt < 8; ++dt)
                #pragma unroll
                for (int r = 0; r < 16; ++r) acc[dt][r] *= sc;
            m_use = mnew;
        }
        float sum = 0.f;
        #pragma unroll
        for (int r = 0; r < 16; ++r) {
            float p = __expf(sacc[r] - m_use);
            sacc[r] = p; sum += p;
        }
        sum += __shfl_xor(sum, 32);
        l_run += sum;

        // ---- P -> bf16 B-frags, slot k = h*8+e.
        // permlane32_swap(a,b): ret[0]=[a_lo|b_lo], ret[1]=[a_hi|b_hi]
        // == exactly (h? partner_b : own_a, h? own_b : partner_a).
        union { int wd[4]; s16x8 v; } f0, f1;
        {
            int w01, w23, w45, w67;
            asm("v_cvt_pk_bf16_f32 %0, %1, %2" : "=v"(w01) : "v"(sacc[0]), "v"(sacc[1]));
            asm("v_cvt_pk_bf16_f32 %0, %1, %2" : "=v"(w23) : "v"(sacc[2]), "v"(sacc[3]));
            asm("v_cvt_pk_bf16_f32 %0, %1, %2" : "=v"(w45) : "v"(sacc[4]), "v"(sacc[5]));
            asm("v_cvt_pk_bf16_f32 %0, %1, %2" : "=v"(w67) : "v"(sacc[6]), "v"(sacc[7]));
            i32x2 r02 = __builtin_amdgcn_permlane32_swap(w01, w45, false, false);
            i32x2 r13 = __builtin_amdgcn_permlane32_swap(w23, w67, false, false);
            f0.wd[0] = r02[0]; f0.wd[1] = r13[0];
            f0.wd[2] = r02[1]; f0.wd[3] = r13[1];
        }
        {
            int w01, w23, w45, w67;
            asm("v_cvt_pk_bf16_f32 %0, %1, %2" : "=v"(w01) : "v"(sacc[8]),  "v"(sacc[9]));
            asm("v_cvt_pk_bf16_f32 %0, %1, %2" : "=v"(w23) : "v"(sacc[10]), "v"(sacc[11]));
            asm("v_cvt_pk_bf16_f32 %0, %1, %2" : "=v"(w45) : "v"(sacc[12]), "v"(sacc[13]));
            asm("v_cvt_pk_bf16_f32 %0, %1, %2" : "=v"(w67) : "v"(sacc[14]), "v"(sacc[15]));
            i32x2 r02 = __builtin_amdgcn_permlane32_swap(w01, w45, false, false);
            i32x2 r13 = __builtin_amdgcn_permlane32_swap(w23, w67, false, false);
            f1.wd[0] = r02[0]; f1.wd[1] = r13[0];
            f1.wd[2] = r02[1]; f1.wd[3] = r13[1];
        }

        // ---- PV: O^T[d][q] += V^T-frag x P-frag (V from LDS)
        const char* vbuf = cbuf + 16384;
        __builtin_amdgcn_s_setprio(1);
        #pragma unroll
        for (int dt = 0; dt < 8; ++dt) {
            s16x8 v0 = *(const s16x8*)(vbuf + (dt) * 1024 + lane * 16);
            s16x8 v1 = *(const s16x8*)(vbuf + (8 + dt) * 1024 + lane * 16);
            acc[dt] = __builtin_amdgcn_mfma_f32_32x32x16_bf16(v0, f0.v, acc[dt], 0, 0, 0);
            acc[dt] = __builtin_amdgcn_mfma_f32_32x32x16_bf16(v1, f1.v, acc[dt], 0, 0, 0);
        }
        __builtin_amdgcn_s_setprio(0);
    }

    // ---- epilogue: packed unnormalized partial + (m,l)
    const int qb = qblk * 4 + w;
    const size_t pb2 = (((size_t)(split * 2 + b) * 256 + qb) * 32) * 256;
    #pragma unroll
    for (int dt = 0; dt < 8; ++dt)
        #pragma unroll
        for (int rg = 0; rg < 4; ++rg) {
            s16x4 st;
            st[0] = f2bf(acc[dt][rg * 4 + 0]);
            st[1] = f2bf(acc[dt][rg * 4 + 1]);
            st[2] = f2bf(acc[dt][rg * 4 + 2]);
            st[3] = f2bf(acc[dt][rg * 4 + 3]);
            *(s16x4*)&part[pb2 + (size_t)(dt * 4 + rg) * 256 + lane * 4] = st;
        }
    if (h == 0) {
        size_t mi = ((size_t)split * (BB * NN) + bN + q) * 2;
        ml[mi] = m_use; ml[mi + 1] = l_run;
    }
}

// ---------------------------------------------------------------------------
// Kernel 3 (legacy, small-ws path): combine packed partials -> yp
// ---------------------------------------------------------------------------
template<int SPLIT>
__global__ __launch_bounds__(256) void combine2_kernel(
    const short* __restrict__ part, const float* __restrict__ ml,
    short* __restrict__ yp)
{
    int gid  = blockIdx.x * 256 + threadIdx.x;
    int lane = gid & 63;
    int slot = (gid >> 6) & 31;
    int qb   = (gid >> 11) & 255;
    int b    = gid >> 19;
    int dt = slot >> 2, rg = slot & 3;
    int l31 = lane & 31, h = lane >> 5;
    int q = qb * 32 + l31;

    float mm[SPLIT], ll[SPLIT];
    float m = -1e30f;
    #pragma unroll
    for (int s = 0; s < SPLIT; ++s) {
        mm[s] = ml[((size_t)s * (BB * NN) + (size_t)b * NN + q) * 2];
        ll[s] = ml[((size_t)s * (BB * NN) + (size_t)b * NN + q) * 2 + 1];
        m = fmaxf(m, mm[s]);
    }
    float den = 0.f, a[SPLIT];
    #pragma unroll
    for (int s = 0; s < SPLIT; ++s) { a[s] = __expf(mm[s] - m); den += a[s] * ll[s]; }
    float o[4] = {0.f, 0.f, 0.f, 0.f};
    #pragma unroll
    for (int s = 0; s < SPLIT; ++s) {
        s16x4 p = *(const s16x4*)&part[((((size_t)(s * 2 + b) * 256 + qb) * 32 + slot) * 64 + lane) * 4];
        #pragma unroll
        for (int j = 0; j < 4; ++j) o[j] += a[s] * bf2f(p[j]);
    }
    float inv = 1.f / den;
    s16x4 st;
    #pragma unroll
    for (int j = 0; j < 4; ++j) st[j] = f2bf(o[j] * inv);
    size_t a2 = ((((size_t)b * 512 + (q >> 4)) * 8 + dt) * 64 + (q & 15) + rg * 16) * 8 + h * 4;
    *(s16x4*)&yp[a2] = st;
}

// ---------------------------------------------------------------------------
// Kernel 4a (big path): z = W*y + b, reading part+ml directly (combine fused)
// ---------------------------------------------------------------------------
template<int SPLIT>
__global__ __launch_bounds__(256) void zgemm_fused_kernel(
    const short* __restrict__ part, const float* __restrict__ ml,
    const short* __restrict__ Wf, const float* __restrict__ wb,
    float* __restrict__ z)
{
    const int blk = blockIdx.x;
    const int b   = blk >> 7;
    const int n0  = (blk & 127) << 6;
    const int tid = threadIdx.x;
    const int lane = tid & 63, w = tid >> 6, lo = lane & 15, g = lane >> 4;
    const int q  = n0 + w * 16 + lo;
    const int qb = q >> 5, l31 = q & 31;

    float mm[SPLIT], ll[SPLIT], a[SPLIT];
    float m = -1e30f;
    #pragma unroll
    for (int s = 0; s < SPLIT; ++s) {
        mm[s] = ml[((size_t)s * (BB * NN) + (size_t)b * NN + q) * 2];
        ll[s] = ml[((size_t)s * (BB * NN) + (size_t)b * NN + q) * 2 + 1];
        m = fmaxf(m, mm[s]);
    }
    float den = 0.f;
    #pragma unroll
    for (int s = 0; s < SPLIT; ++s) { a[s] = __expf(mm[s] - m); den += a[s] * ll[s]; }
    float inv = 1.f / den;
    #pragma unroll
    for (int s = 0; s < SPLIT; ++s) a[s] *= inv;

    // A-frags: afr[k][e] = y[q][k*32 + g*8 + e], normalized from partials
    s16x8 afr[8];
    #pragma unroll
    for (int k = 0; k < 8; ++k) {
        float o[8] = {0.f, 0.f, 0.f, 0.f, 0.f, 0.f, 0.f, 0.f};
        #pragma unroll
        for (int s = 0; s < SPLIT; ++s) {
            size_t base = ((((size_t)(s * 2 + b) * 256 + qb) * 32 + (k * 4 + g)) * 64 + l31) * 4;
            s16x4 plo = *(const s16x4*)&part[base];
            s16x4 phi = *(const s16x4*)&part[base + 128];
            #pragma unroll
            for (int j = 0; j < 4; ++j) {
                o[j]     += a[s] * bf2f(plo[j]);
                o[4 + j] += a[s] * bf2f(phi[j]);
            }
        }
        #pragma unroll
        for (int j = 0; j < 8; ++j) afr[k][j] = f2bf(o[j]);
    }

    for (int ot = 0; ot < 16; ++ot) {
        f32x4 acc = {0.f, 0.f, 0.f, 0.f};
        #pragma unroll
        for (int k = 0; k < 8; ++k) {
            s16x8 bfr = *(const s16x8*)&Wf[(size_t)((3 * 16 + ot) * 8 + k) * 512 + lane * 8];
            acc = __builtin_amdgcn_mfma_f32_16x16x32_bf16(afr[k], bfr, acc, 0, 0, 0);
        }
        float bias = wb[ot * 16 + lo];
        float4 st = {acc[0] + bias, acc[1] + bias, acc[2] + bias, acc[3] + bias};
        *(float4*)&z[((size_t)b * CIc + ot * 16 + lo) * NN + n0 + w * 16 + g * 4] = st;
    }
}

// ---------------------------------------------------------------------------
// Kernel 4b (legacy, small-ws path): z = W*y + b from packed yp
// ---------------------------------------------------------------------------
__global__ __launch_bounds__(256) void zgemm_kernel(
    const short* __restrict__ yp, const short* __restrict__ Wf,
    const float* __restrict__ wb, float* __restrict__ z)
{
    const int blk = blockIdx.x;
    const int b   = blk >> 7;
    const int n0  = (blk & 127) << 6;
    const int tid = threadIdx.x;
    const int lane = tid & 63, w = tid >> 6, lo = lane & 15, g = lane >> 4;

    s16x8 afr[8];
    #pragma unroll
    for (int k = 0; k < 8; ++k)
        afr[k] = *(const s16x8*)&yp[((((size_t)b * 512 + (n0 >> 4) + w) * 8 + k) * 64 + lane) * 8];

    for (int ot = 0; ot < 16; ++ot) {
        f32x4 acc = {0.f, 0.f, 0.f, 0.f};
        #pragma unroll
        for (int k = 0; k < 8; ++k) {
            s16x8 bfr = *(const s16x8*)&Wf[(size_t)((3 * 16 + ot) * 8 + k) * 512 + lane * 8];
            acc = __builtin_amdgcn_mfma_f32_16x16x32_bf16(afr[k], bfr, acc, 0, 0, 0);
        }
        float bias = wb[ot * 16 + lo];
        float4 st = {acc[0] + bias, acc[1] + bias, acc[2] + bias, acc[3] + bias};
        *(float4*)&z[((size_t)b * CIc + ot * 16 + lo) * NN + n0 + w * 16 + g * 4] = st;
    }
}

// ---------------------------------------------------------------------------
// Kernel 5: per-channel batch stats (mean, rsqrt(var+eps)); 1 block/channel
// ---------------------------------------------------------------------------
__global__ __launch_bounds__(256) void bnstats_kernel(
    const float* __restrict__ z, float* __restrict__ stats)
{
    const int o = blockIdx.x;
    const int tid = threadIdx.x;
    float s = 0.f, s2 = 0.f;
    for (int b = 0; b < BB; ++b) {
        const float* row = &z[((size_t)b * CIc + o) * NN];
        for (int i = tid * 4; i < NN; i += 1024) {
            float4 v = *(const float4*)&row[i];
            s  += v.x + v.y + v.z + v.w;
            s2 += v.x * v.x + v.y * v.y + v.z * v.z + v.w * v.w;
        }
    }
    #pragma unroll
    for (int off = 1; off < 64; off <<= 1) {
        s  += __shfl_xor(s, off);
        s2 += __shfl_xor(s2, off);
    }
    __shared__ float rs[8];
    if ((tid & 63) == 0) { rs[tid >> 6] = s; rs[4 + (tid >> 6)] = s2; }
    __syncthreads();
    if (tid == 0) {
        float S  = rs[0] + rs[1] + rs[2] + rs[3];
        float S2 = rs[4] + rs[5] + rs[6] + rs[7];
        float mean = S / (float)(BB * NN);
        float var  = S2 / (float)(BB * NN) - mean * mean;
        stats[o * 2]     = mean;
        stats[o * 2 + 1] = rsqrtf(var + 1e-5f);
    }
}

// ---------------------------------------------------------------------------
// Kernel 6: in-place BN apply on d_out
// ---------------------------------------------------------------------------
__global__ __launch_bounds__(256) void bnapply_kernel(
    float* __restrict__ z, const float* __restrict__ stats,
    const float* __restrict__ gamma, const float* __restrict__ beta)
{
    int gid = blockIdx.x * 256 + threadIdx.x;
    int idx4 = gid * 4;
    int o = (idx4 >> 13) & 255;
    float mean = stats[o * 2], rs = stats[o * 2 + 1];
    float ga = gamma[o], be = beta[o];
    float4 v = *(const float4*)&z[idx4];
    v.x = (v.x - mean) * rs * ga + be;
    v.y = (v.y - mean) * rs * ga + be;
    v.z = (v.z - mean) * rs * ga + be;
    v.w = (v.w - mean) * rs * ga + be;
    *(float4*)&z[idx4] = v;
}

// ---------------------------------------------------------------------------
extern "C" void kernel_launch(void* const* d_in, const int* in_sizes, int n_in,
                              void* d_out, int out_size, void* d_ws, size_t ws_size,
                              hipStream_t stream) {
    const float* x    = (const float*)d_in[0];
    const float* g_w  = (const float*)d_in[1];
    const float* g_b  = (const float*)d_in[2];
    const float* th_w = (const float*)d_in[3];
    const float* th_b = (const float*)d_in[4];
    const float* ph_w = (const float*)d_in[5];
    const float* ph_b = (const float*)d_in[6];
    const float* w_w  = (const float*)d_in[7];
    const float* w_b  = (const float*)d_in[8];
    const float* bn_g = (const float*)d_in[9];
    const float* bn_b = (const float*)d_in[10];

    char* ws = (char*)d_ws;
    short* Qb    = (short*)ws;                         // 8 MiB (reused as yp)
    short* Kf    = (short*)(ws + 8  * 1048576);        // 8 MiB
    short* Vf    = (short*)(ws + 16 * 1048576);        // 8 MiB
    float* ml    = (float*)(ws + 24 * 1048576);        // <= 512 KiB
    float* stats = (float*)(ws + 24 * 1048576 + 524288);
    short* Wfb   = (short*)(ws + 25 * 1048576);        // 512 KiB
    float* z     = (float*)d_out;

    const size_t need4 = (size_t)26 * 1048576 + (size_t)4 * BB * NN * CIc * 2;
    const bool  big    = ws_size >= need4;

    pack_kernel<<<128, 256, 0, stream>>>(th_w, ph_w, g_w, w_w, Wfb);
    proj_kernel<<<768, 256, 0, stream>>>(x, Wfb, th_b, ph_b, g_b, Qb, Kf, Vf);

    if (big) {
        short* part = (short*)(ws + 26 * 1048576);     // 32 MiB
        attn2_kernel<4><<<512, 256, 0, stream>>>(Qb, Kf, Vf, part, ml);
        zgemm_fused_kernel<4><<<256, 256, 0, stream>>>(part, ml, Wfb, w_b, z);
    } else {
        short* part = (short*)d_out;                   // 2 splits fit d_out exactly
        attn2_kernel<2><<<256, 256, 0, stream>>>(Qb, Kf, Vf, part, ml);
        combine2_kernel<2><<<4096, 256, 0, stream>>>(part, ml, Qb);
        zgemm_kernel<<<256, 256, 0, stream>>>(Qb, Wfb, w_b, z);
    }

    bnstats_kernel<<<256, 256, 0, stream>>>(z, stats);
    bnapply_kernel<<<4096, 256, 0, stream>>>(z, stats, bn_g, bn_b);
}